// Round 12
// baseline (518.548 us; speedup 1.0000x reference)
//
#include <hip/hip_runtime.h>
#include <hip/hip_fp16.h>
#include <math.h>

// Problem constants (fixed by the reference)
#define C_   4096
#define H_   256
#define V_   16000
#define SPW  32
#define NB   32    // N (batch)
#define TT   128   // T (sequence length)
#define NTOK ((TT - 1) * NB)          // 4064 token transitions
#define NITEM (NTOK * SPW)            // 130048 (nt, i) row-uses
#define GEMM_K 768                    // 3 x 256 split-fp16 segments
#define LOG2E 1.44269504088896340736f
#define LN2   0.69314718055994530942f

// raw hardware transcendentals (v_exp_f32 computes 2^x, v_log_f32 is log2).
__device__ inline float fexp2(float x) { return __builtin_amdgcn_exp2f(x); }
__device__ inline float flog2(float x) { return __builtin_amdgcn_logf(x); }

// ---------------------------------------------------------------------------
// Workspace layout (float offsets). Total ~27.0M floats = ~108 MB.
// ---------------------------------------------------------------------------
static const size_t OFF_TL    = 0;                                   // C*C transition logits
static const size_t OFF_RES   = OFF_TL   + (size_t)C_ * C_;          // C*H spare: lse partials (4 MB exact)
static const size_t OFF_STMP  = OFF_RES  + (size_t)C_ * H_;          // C   start pre-softmax
static const size_t OFF_START = OFF_STMP + C_;                       // C   start log-probs
static const size_t OFF_LSE1  = OFF_START + C_;                      // C
static const size_t OFF_LSE2  = OFF_LSE1 + C_;                       // C (spare)
static const size_t OFF_RMAX  = OFF_LSE2 + C_;                       // C (unsigned, encoded-float max)
static const size_t OFF_RSUM  = OFF_RMAX + C_;                       // C
static const size_t OFF_DEN   = OFF_RSUM + C_;                       // C emission row log-denominator
static const size_t OFF_LOGZ  = OFF_DEN  + C_;                       // [0,32) natural; [32,64) base-2
static const size_t OFF_ELBO  = OFF_LOGZ + 64;                       // done counter lives here
static const size_t OFF_EWT   = OFF_ELBO + 16;                       // V*H region (Ap/Bp early, ewT later)
static const size_t OFF_L     = OFF_EWT  + (size_t)V_ * H_;          // V*SPW masked emission logits
static const size_t OFF_OBS   = OFF_L    + (size_t)V_ * SPW;         // now: elbo partials (obs deleted)
static const size_t OFF_PHI   = OFF_OBS  + (size_t)NB * TT * SPW;    // phiN[t,n,i,j] * LOG2E (base-2)
static const size_t OFF_ALPH  = OFF_PHI  + (size_t)NTOK * SPW * SPW; // (T-1)*N*SPW (base-2)
static const size_t OFF_BETA  = OFF_ALPH + (size_t)NTOK * SPW;       // (T-1)*N*SPW (base-2)

// lse partials: part[row][slice], 4096 x 128 float2 = 1,048,576 floats (exact RES fit)
static const size_t OFF_PART  = OFF_RES;
// elbo per-block partials: NTOK doubles in the freed obs region (8B aligned)
static const size_t OFF_EPART = OFF_OBS;

// MLP GEMM scratch aliased onto TL region (dead until gemm_bt writes TL):
static const size_t OFF_XP    = OFF_TL;                                   // 12288x768 us
static const size_t OFF_HP    = OFF_TL + (size_t)3 * C_ * GEMM_K / 2;     // 12288x768 us
static const size_t OFF_W1P   = OFF_TL + (size_t)6 * C_ * GEMM_K / 2;     // 3 x 256x768 us
static const size_t OFF_W2P   = OFF_W1P + (size_t)3 * 256 * GEMM_K / 2;

// Ap/Bp (TL-GEMM operands) in the ewT region; ewT overwrites them after gemm_bt.
static const size_t OFF_AP    = OFF_EWT;                              // 4096x768 us
static const size_t OFF_BP    = OFF_EWT + (size_t)C_ * GEMM_K / 2;    // 4096x768 us

// res_e aliased onto phi region (phi written much later by phi_gather).
static const size_t OFF_RES_E = OFF_PHI + (size_t)C_ * H_;

// Inverted-index scratch aliased onto alpha/beta region (dead until scan).
static const size_t OFF_CNT   = OFF_ALPH;            // 4096 int
static const size_t OFF_OFFS  = OFF_ALPH + 4096;     // 4097 int (pad to 4112)
static const size_t OFF_CUR   = OFF_ALPH + 8208;     // 4096 int
static const size_t OFF_ENT   = OFF_ALPH + 12304;    // NITEM int

// Monotone float<->uint encoding for atomicMax on floats (handles negatives)
__device__ inline unsigned enc_f(float f) {
    unsigned u = __float_as_uint(f);
    return (u & 0x80000000u) ? ~u : (u | 0x80000000u);
}
__device__ inline float dec_f(unsigned k) {
    return (k & 0x80000000u) ? __uint_as_float(k ^ 0x80000000u) : __uint_as_float(~k);
}

__device__ inline void split_h(float v, unsigned short& hi, unsigned short& lo) {
    __half h = __float2half(v);
    __half l = __float2half(v - __half2float(h));
    __builtin_memcpy(&hi, &h, 2);
    __builtin_memcpy(&lo, &l, 2);
}

typedef __attribute__((ext_vector_type(8))) short short8;
typedef __attribute__((ext_vector_type(4))) float floatx4;

#define GLB(p)  ((const __attribute__((address_space(1))) unsigned int*)(p))
#define LDSP(p) ((__attribute__((address_space(3))) unsigned int*)(p))

// ---------------------------------------------------------------------------
// K1: pack everything to split-fp16; trailing 16 blocks do accumulator init.
// ---------------------------------------------------------------------------
__global__ __launch_bounds__(256) void pack_all_kernel(
    const float* __restrict__ se, const float* __restrict__ ste, const float* __restrict__ pe,
    const float* __restrict__ nsp,
    const float* __restrict__ w1_0, const float* __restrict__ w1_1, const float* __restrict__ w1_2,
    const float* __restrict__ w2_0, const float* __restrict__ w2_1, const float* __restrict__ w2_2,
    unsigned short* __restrict__ Xp, unsigned short* __restrict__ Bp,
    unsigned short* __restrict__ W1p, unsigned short* __restrict__ W2p,
    unsigned* __restrict__ rowmax, float* __restrict__ rowsum,
    int* __restrict__ cnt, float* __restrict__ s_tmp, unsigned* __restrict__ done)
{
    __shared__ float tile_s[32][33];
    int blk = blockIdx.x;
    if (blk < 4096) {
        bool isB = blk >= 3072;
        int e4 = (isB ? blk - 3072 : blk) * 256 + threadIdx.x;
        int r = e4 >> 6;
        int c = (e4 & 63) * 4;
        const float* src;
        unsigned short* dst;
        if (isB) { src = nsp + (size_t)r * H_; dst = Bp; }
        else {
            int inst = r >> 12;
            int rl = r & 4095;
            src = (inst == 0 ? se : inst == 1 ? ste : pe) + (size_t)rl * H_;
            dst = Xp;
        }
        float4 v = *(const float4*)(src + c);
        float vv[4] = {v.x, v.y, v.z, v.w};
        union { unsigned short s[4]; ushort4 u; } hi, lo;
#pragma unroll
        for (int q = 0; q < 4; ++q) split_h(vv[q], hi.s[q], lo.s[q]);
        size_t base = (size_t)r * GEMM_K + c;
        if (!isB) {   // A-layout [hi | lo | hi]
            *(ushort4*)&dst[base]       = hi.u;
            *(ushort4*)&dst[base + 256] = lo.u;
            *(ushort4*)&dst[base + 512] = hi.u;
        } else {      // B-layout [hi | hi | lo]
            *(ushort4*)&dst[base]       = hi.u;
            *(ushort4*)&dst[base + 256] = hi.u;
            *(ushort4*)&dst[base + 512] = lo.u;
        }
    } else if (blk < 4480) {
        int b = blk - 4096;
        int mat = b >> 6, tile = b & 63;
        int n0 = (tile & 7) * 32, k0 = (tile >> 3) * 32;
        const float* W = mat == 0 ? w1_0 : mat == 1 ? w1_1 : mat == 2 ? w1_2
                       : mat == 3 ? w2_0 : mat == 4 ? w2_1 : w2_2;
        unsigned short* dst = (mat < 3) ? W1p + (size_t)mat * 256 * GEMM_K
                                        : W2p + (size_t)(mat - 3) * 256 * GEMM_K;
        int tx = threadIdx.x & 31, ty = threadIdx.x >> 5;
#pragma unroll
        for (int q = 0; q < 4; ++q)
            tile_s[ty + 8 * q][tx] = W[(size_t)(k0 + ty + 8 * q) * 256 + n0 + tx];
        __syncthreads();
#pragma unroll
        for (int q = 0; q < 4; ++q) {
            float v = tile_s[tx][ty + 8 * q];
            unsigned short hi, lo;
            split_h(v, hi, lo);
            size_t ob = (size_t)(n0 + ty + 8 * q) * GEMM_K + k0 + tx;
            dst[ob] = hi; dst[ob + 256] = hi; dst[ob + 512] = lo;
        }
    } else {
        int i = (blk - 4480) * 256 + threadIdx.x;   // < 4096
        rowmax[i] = 0u; rowsum[i] = 0.f; cnt[i] = 0; s_tmp[i] = 0.f;
        if (blk == 4480 && threadIdx.x == 0) *done = 0u;
    }
}

// ---------------------------------------------------------------------------
// Shared GEMM core: 128x128 tile, 4 waves of 64x64, f16 16x16x32 MFMA, K=768.
// ---------------------------------------------------------------------------
#define GEMM_PROLOGUE(APTR, BPTR)                                              \
    __shared__ __align__(16) unsigned short As[128 * 64];                      \
    __shared__ __align__(16) unsigned short Bs[128 * 64];                      \
    int tid = threadIdx.x;                                                     \
    int wave = tid >> 6, lane = tid & 63;                                      \
    int wm = (wave & 1) * 64, wn = (wave >> 1) * 64;                           \
    int l15 = lane & 15, quad = lane >> 4;                                     \
    floatx4 acc[4][4] = {};                                                    \
    int c0row = tid >> 3;                                                      \
    int c0col = (tid & 7) * 8;                                                 \
    for (int k0 = 0; k0 < GEMM_K; k0 += 64) {                                  \
        __syncthreads();                                                       \
        _Pragma("unroll")                                                      \
        for (int q = 0; q < 4; ++q) {                                          \
            int row = c0row + q * 32;                                          \
            const unsigned short* ga = (APTR) + (size_t)(i0 + row) * GEMM_K + k0 + c0col; \
            const unsigned short* gb = (BPTR) + (size_t)(j0 + row) * GEMM_K + k0 + c0col; \
            __builtin_amdgcn_global_load_lds(GLB(ga), LDSP(&As[(size_t)row * 64 + c0col]), 16, 0, 0); \
            __builtin_amdgcn_global_load_lds(GLB(gb), LDSP(&Bs[(size_t)row * 64 + c0col]), 16, 0, 0); \
        }                                                                      \
        __syncthreads();                                                       \
        _Pragma("unroll")                                                      \
        for (int ks = 0; ks < 64; ks += 32) {                                  \
            short8 af[4], bfr[4];                                              \
            _Pragma("unroll")                                                  \
            for (int mi = 0; mi < 4; ++mi)                                     \
                af[mi] = *(const short8*)&As[(wm + mi * 16 + l15) * 64 + ks + quad * 8]; \
            _Pragma("unroll")                                                  \
            for (int ni = 0; ni < 4; ++ni)                                     \
                bfr[ni] = *(const short8*)&Bs[(wn + ni * 16 + l15) * 64 + ks + quad * 8]; \
            _Pragma("unroll")                                                  \
            for (int mi = 0; mi < 4; ++mi)                                     \
                _Pragma("unroll")                                              \
                for (int ni = 0; ni < 4; ++ni)                                 \
                    acc[mi][ni] = __builtin_amdgcn_mfma_f32_16x16x32_f16(      \
                        af[mi], bfr[ni], acc[mi][ni], 0, 0, 0);                \
        }                                                                      \
    }

// ---------------------------------------------------------------------------
// K2: MLP layer 1: H = relu(X@W1 + b1), packed split-fp16 out (A-layout).
// ---------------------------------------------------------------------------
__global__ __launch_bounds__(256) void gemm_layer1(
    const unsigned short* __restrict__ Xp, const unsigned short* __restrict__ Wp,
    const float* __restrict__ b0, const float* __restrict__ b1, const float* __restrict__ b2,
    unsigned short* __restrict__ Hp)
{
    int i0 = blockIdx.y * 128, j0 = blockIdx.x * 128;
    int inst = blockIdx.y >> 5;
    const unsigned short* Wbase = Wp + (size_t)inst * 256 * GEMM_K;
    const float* bias = inst == 0 ? b0 : (inst == 1 ? b1 : b2);
    GEMM_PROLOGUE(Xp, Wbase)
#pragma unroll
    for (int mi = 0; mi < 4; ++mi) {
#pragma unroll
        for (int reg = 0; reg < 4; ++reg) {
            int row = i0 + wm + mi * 16 + quad * 4 + reg;
#pragma unroll
            for (int ni = 0; ni < 4; ++ni) {
                int col = j0 + wn + ni * 16 + l15;
                float h = fmaxf(acc[mi][ni][reg] + bias[col], 0.f);
                unsigned short hi, lo;
                split_h(h, hi, lo);
                size_t base = (size_t)row * GEMM_K + col;
                Hp[base] = hi; Hp[base + 256] = lo; Hp[base + 512] = hi;
            }
        }
    }
}

// ---------------------------------------------------------------------------
// K3: MLP layer 2: Z = relu(H@W2 + b2) + X, per-instance epilogue.
// ---------------------------------------------------------------------------
__global__ __launch_bounds__(256) void gemm_layer2(
    const unsigned short* __restrict__ Hp, const unsigned short* __restrict__ Wp,
    const float* __restrict__ b0, const float* __restrict__ b1, const float* __restrict__ b2,
    const float* __restrict__ x0, const float* __restrict__ x1, const float* __restrict__ x2,
    const float* __restrict__ sow, float* __restrict__ s_tmp,
    unsigned short* __restrict__ Ap, float* __restrict__ res_e)
{
    int i0 = blockIdx.y * 128, j0 = blockIdx.x * 128;
    int inst = blockIdx.y >> 5;
    const unsigned short* Wbase = Wp + (size_t)inst * 256 * GEMM_K;
    const float* bias = inst == 0 ? b0 : (inst == 1 ? b1 : b2);
    const float* X = inst == 0 ? x0 : (inst == 1 ? x1 : x2);
    GEMM_PROLOGUE(Hp, Wbase)
#pragma unroll
    for (int mi = 0; mi < 4; ++mi) {
#pragma unroll
        for (int reg = 0; reg < 4; ++reg) {
            int row = i0 + wm + mi * 16 + quad * 4 + reg;
            int rl = row & 4095;
            float ps = 0.f;
#pragma unroll
            for (int ni = 0; ni < 4; ++ni) {
                int col = j0 + wn + ni * 16 + l15;
                float z = fmaxf(acc[mi][ni][reg] + bias[col], 0.f)
                        + X[(size_t)rl * H_ + col];
                if (inst == 0) {
                    ps += z * sow[col];
                } else if (inst == 1) {
                    unsigned short hi, lo;
                    split_h(z, hi, lo);
                    size_t base = (size_t)rl * GEMM_K + col;
                    Ap[base] = hi; Ap[base + 256] = lo; Ap[base + 512] = hi;
                } else {
                    res_e[(size_t)rl * H_ + col] = z;
                }
            }
            if (inst == 0) {
                ps += __shfl_xor(ps, 1);
                ps += __shfl_xor(ps, 2);
                ps += __shfl_xor(ps, 4);
                ps += __shfl_xor(ps, 8);
                if (l15 == 0) atomicAdd(&s_tmp[rl], ps);
            }
        }
    }
}

// ---------------------------------------------------------------------------
// K4: TL = Ap.Bp^T with per-row lse partials: 3 shuffle-merge levels only,
// 2 partials per 16-lane group -> part[row][128 slices].  No atomics.
// ---------------------------------------------------------------------------
__global__ __launch_bounds__(256) void gemm_bt_kernel(
    const unsigned short* __restrict__ Ap, const unsigned short* __restrict__ Bp,
    float* __restrict__ Cmat, float2* __restrict__ part)
{
    int i0 = blockIdx.y * 128, j0 = blockIdx.x * 128;
    GEMM_PROLOGUE(Ap, Bp)
    int slice = (blockIdx.x * 2 + (wave >> 1)) * 2;
#pragma unroll
    for (int mi = 0; mi < 4; ++mi) {
#pragma unroll
        for (int reg = 0; reg < 4; ++reg) {
            int row = i0 + wm + mi * 16 + quad * 4 + reg;
            float* crow = Cmat + (size_t)row * C_ + j0 + wn;
#pragma unroll
            for (int ni = 0; ni < 4; ++ni)
                crow[ni * 16 + l15] = acc[mi][ni][reg];
            float m = fmaxf(fmaxf(acc[mi][0][reg], acc[mi][1][reg]),
                            fmaxf(acc[mi][2][reg], acc[mi][3][reg]));
            float s = __expf(acc[mi][0][reg] - m) + __expf(acc[mi][1][reg] - m)
                    + __expf(acc[mi][2][reg] - m) + __expf(acc[mi][3][reg] - m);
#pragma unroll
            for (int off = 1; off <= 4; off <<= 1) {
                float mo = __shfl_xor(m, off);
                float so = __shfl_xor(s, off);
                float M = fmaxf(m, mo);
                s = s * __expf(m - M) + so * __expf(mo - M);
                m = M;
            }
            if ((l15 & 7) == 0)
                part[(size_t)row * 128 + slice + (l15 >> 3)] = make_float2(m, s);
        }
    }
}

// ---------------------------------------------------------------------------
// K5: transpose e_out_w (H,V) -> ewT (V,H)  (overwrites dead Ap/Bp region)
// ---------------------------------------------------------------------------
__global__ __launch_bounds__(256) void transpose_kernel(
    const float* __restrict__ W, float* __restrict__ WT)
{
    __shared__ float tile[32][33];
    int tx = threadIdx.x & 31, ty = threadIdx.x >> 5;
    int v0 = blockIdx.x * 32, h0 = blockIdx.y * 32;
#pragma unroll
    for (int q = 0; q < 4; ++q)
        tile[ty + 8 * q][tx] = W[(size_t)(h0 + ty + 8 * q) * V_ + v0 + tx];
    __syncthreads();
#pragma unroll
    for (int q = 0; q < 4; ++q)
        WT[(size_t)(v0 + ty + 8 * q) * H_ + h0 + tx] = tile[tx][ty + 8 * q];
}

// ---------------------------------------------------------------------------
// K6: masked emission logits + FUSED per-state rowmax scatter (deduped).
// ---------------------------------------------------------------------------
__global__ __launch_bounds__(256) void em_logits_kernel(
    const float* __restrict__ res_pre, const float* __restrict__ ewT,
    const float* __restrict__ eob, const int* __restrict__ w2s,
    float* __restrict__ L, unsigned* __restrict__ rowmax)
{
    int v = blockIdx.x;
    __shared__ __align__(16) float wv[H_];
    __shared__ int st[32];
    wv[threadIdx.x] = ewT[(size_t)v * H_ + threadIdx.x];
    int g = threadIdx.x >> 3;
    int l = threadIdx.x & 7;
    int c = w2s[v * SPW + g];
    if (l == 0) st[g] = c;
    __syncthreads();
    const float4* row4 = (const float4*)(res_pre + (size_t)c * H_);
    const float4* wv4 = (const float4*)wv;
    float sum = 0.f;
#pragma unroll
    for (int m = 0; m < 8; ++m) {
        float4 r = row4[l + m * 8];
        float4 w = wv4[l + m * 8];
        sum += r.x * w.x + r.y * w.y + r.z * w.z + r.w * w.w;
    }
    sum += __shfl_xor(sum, 1);
    sum += __shfl_xor(sum, 2);
    sum += __shfl_xor(sum, 4);
    if (l == 0) {
        float logit = sum + eob[v];
        L[v * SPW + g] = logit;
        bool dup = false;
        for (int kp = 0; kp < g; ++kp) if (st[kp] == c) { dup = true; break; }
        if (!dup) atomicMax(&rowmax[c], enc_f(logit));
    }
}

// ---------------------------------------------------------------------------
// K7: scatter per-state sum(exp(x-max)), deduping repeated states
// ---------------------------------------------------------------------------
__global__ __launch_bounds__(256) void row_sum_kernel(
    const int* __restrict__ w2s, const float* __restrict__ L,
    const unsigned* __restrict__ rowmax, float* __restrict__ rowsum)
{
    __shared__ int st[8][32];
    int vl = threadIdx.x >> 5, k = threadIdx.x & 31;
    int v = blockIdx.x * 8 + vl;
    st[vl][k] = w2s[v * SPW + k];
    __syncthreads();
    int c = st[vl][k];
    bool dup = false;
    for (int kp = 0; kp < k; ++kp) if (st[vl][kp] == c) { dup = true; break; }
    if (!dup) atomicAdd(&rowsum[c], expf(L[v * SPW + k] - dec_f(rowmax[c])));
}

// ---------------------------------------------------------------------------
// K8: fused: denom (blocks 0..15) + hist (16..523) + lse1 fold (one wave per
// row, 128 partials each: 524..1547) + start log_softmax (block 1548).
// ---------------------------------------------------------------------------
__global__ __launch_bounds__(256) void denom_hist_lse_kernel(
    const unsigned* __restrict__ rowmax, const float* __restrict__ rowsum,
    float* __restrict__ denom, const int* __restrict__ text,
    const int* __restrict__ w2s, int* __restrict__ count,
    const float2* __restrict__ part, float* __restrict__ lse1,
    const float* __restrict__ s_tmp, float* __restrict__ startl)
{
    int blk = blockIdx.x;
    if (blk < 16) {
        int c = blk * 256 + threadIdx.x;
        unsigned k = rowmax[c];
        denom[c] = (k == 0u) ? -INFINITY : (dec_f(k) + logf(rowsum[c]));
    } else if (blk < 16 + NITEM / 256) {
        int item = (blk - 16) * 256 + threadIdx.x;
        int i  = item & 31;
        int nt = item >> 5;
        int t = nt >> 5, n = nt & 31;
        int v0 = text[n * TT + t];
        int ci = w2s[v0 * SPW + i];
        atomicAdd(&count[ci], 1);
    } else if (blk < 16 + NITEM / 256 + 1024) {
        int row = (blk - 16 - NITEM / 256) * 4 + (threadIdx.x >> 6);
        int lane = threadIdx.x & 63;
        const float2* pr = part + (size_t)row * 128;
        float2 p0 = pr[lane];
        float2 p1 = pr[64 + lane];
        float m = fmaxf(p0.x, p1.x);
        float s = p0.y * __expf(p0.x - m) + p1.y * __expf(p1.x - m);
#pragma unroll
        for (int off = 1; off <= 32; off <<= 1) {
            float mo = __shfl_xor(m, off);
            float so = __shfl_xor(s, off);
            float M = fmaxf(m, mo);
            s = s * __expf(m - M) + so * __expf(mo - M);
            m = M;
        }
        if (lane == 0) lse1[row] = m + logf(s);
    } else {
        __shared__ float red_m[4];
        __shared__ float red_s[4];
        int t = threadIdx.x;
        float v[16];
        float mx = -INFINITY;
#pragma unroll
        for (int q = 0; q < 16; ++q) { v[q] = s_tmp[t + q * 256]; mx = fmaxf(mx, v[q]); }
#pragma unroll
        for (int off = 32; off; off >>= 1) mx = fmaxf(mx, __shfl_xor(mx, off));
        if ((t & 63) == 0) red_m[t >> 6] = mx;
        __syncthreads();
        float M = fmaxf(fmaxf(red_m[0], red_m[1]), fmaxf(red_m[2], red_m[3]));
        float sm = 0.f;
#pragma unroll
        for (int q = 0; q < 16; ++q) sm += __expf(v[q] - M);
#pragma unroll
        for (int off = 32; off; off >>= 1) sm += __shfl_xor(sm, off);
        if ((t & 63) == 0) red_s[t >> 6] = sm;
        __syncthreads();
        float S = red_s[0] + red_s[1] + red_s[2] + red_s[3];
        float lg = logf(S);
#pragma unroll
        for (int q = 0; q < 16; ++q) startl[t + q * 256] = (v[q] - M) - lg;
    }
}

// ---------------------------------------------------------------------------
// K9: single-block 1024-thread prefix scan of counts.
// ---------------------------------------------------------------------------
__global__ __launch_bounds__(1024) void prefix_kernel(
    const int* __restrict__ count, int* __restrict__ offs, int* __restrict__ cursor)
{
    __shared__ int buf[1024];
    int t = threadIdx.x;
    int c0 = count[t * 4 + 0], c1 = count[t * 4 + 1];
    int c2 = count[t * 4 + 2], c3 = count[t * 4 + 3];
    int s = c0 + c1 + c2 + c3;
    buf[t] = s;
    __syncthreads();
    for (int d = 1; d < 1024; d <<= 1) {
        int v = (t >= d) ? buf[t - d] : 0;
        __syncthreads();
        buf[t] += v;
        __syncthreads();
    }
    int excl = buf[t] - s;
    offs[t * 4 + 0] = excl; cursor[t * 4 + 0] = excl; excl += c0;
    offs[t * 4 + 1] = excl; cursor[t * 4 + 1] = excl; excl += c1;
    offs[t * 4 + 2] = excl; cursor[t * 4 + 2] = excl; excl += c2;
    offs[t * 4 + 3] = excl; cursor[t * 4 + 3] = excl;
    if (t == 1023) offs[4096] = buf[1023];
}

// ---------------------------------------------------------------------------
// K10: index fill (obs deleted — computed inline in phi_gather now)
// ---------------------------------------------------------------------------
__global__ void fill_kernel(const int* __restrict__ text, const int* __restrict__ w2s,
                            int* __restrict__ cursor, int* __restrict__ entries)
{
    int item = blockIdx.x * 256 + threadIdx.x;
    int i  = item & 31;
    int nt = item >> 5;
    int t = nt >> 5, n = nt & 31;
    int v0 = text[n * TT + t];
    int ci = w2s[v0 * SPW + i];
    int pos = atomicAdd(&cursor[ci], 1);
    entries[pos] = item;
}

// ---------------------------------------------------------------------------
// K11: phi gather, inverted, obs computed inline (Lm/den gathers, L1-served).
// phiN layout: [t, n, i, j] (j innermost), scaled by LOG2E (base-2 domain).
// ---------------------------------------------------------------------------
__global__ __launch_bounds__(256) void phi_gather_kernel(
    const float* __restrict__ TL, const int* __restrict__ offs, const int* __restrict__ entries,
    const float* __restrict__ lse1, const float* __restrict__ start_log,
    const float* __restrict__ Lm, const float* __restrict__ den,
    const int* __restrict__ text, const int* __restrict__ w2s, float* __restrict__ phiN)
{
    int ci = blockIdx.x;
    __shared__ float row[C_];   // 16 KB
    {
        const float4* src = (const float4*)(TL + (size_t)ci * C_);
        float4* dst = (float4*)row;
        for (int q = threadIdx.x; q < C_ / 4; q += 256) dst[q] = src[q];
    }
    __syncthreads();
    float abase = -lse1[ci];
    float st = start_log[ci];
    float dci = den[ci];
    int beg = offs[ci], end = offs[ci + 1];
    int g = threadIdx.x >> 5, lane = threadIdx.x & 31;
    for (int idx = beg + g; idx < end; idx += 8) {
        int item = entries[idx];
        int i  = item & 31;
        int nt = item >> 5;
        int t = nt >> 5, n = nt & 31;
        int v1 = text[n * TT + t + 1];
        int cj = w2s[v1 * SPW + lane];
        float ob = Lm[v1 * SPW + lane] - den[cj];
        float a = abase;
        if (t == 0) {
            int v0 = text[n * TT];
            a += st + (Lm[v0 * SPW + i] - dci);
        }
        phiN[(size_t)nt * 1024 + i * 32 + lane] = (row[cj] + a + ob) * LOG2E;
    }
}

// tree helpers over a 16-register panel (explicit log-depth reductions)
__device__ inline float tree_max16(const float* x) {
    float r0 = fmaxf(x[0], x[8]),  r1 = fmaxf(x[1], x[9]);
    float r2 = fmaxf(x[2], x[10]), r3 = fmaxf(x[3], x[11]);
    float r4 = fmaxf(x[4], x[12]), r5 = fmaxf(x[5], x[13]);
    float r6 = fmaxf(x[6], x[14]), r7 = fmaxf(x[7], x[15]);
    r0 = fmaxf(r0, r4); r1 = fmaxf(r1, r5); r2 = fmaxf(r2, r6); r3 = fmaxf(r3, r7);
    r0 = fmaxf(r0, r2); r1 = fmaxf(r1, r3);
    return fmaxf(r0, r1);
}
__device__ inline float tree_sum_exp2_16(const float* x, float mx) {
    float e0 = fexp2(x[0] - mx),  e1 = fexp2(x[1] - mx);
    float e2 = fexp2(x[2] - mx),  e3 = fexp2(x[3] - mx);
    float e4 = fexp2(x[4] - mx),  e5 = fexp2(x[5] - mx);
    float e6 = fexp2(x[6] - mx),  e7 = fexp2(x[7] - mx);
    float e8 = fexp2(x[8] - mx),  e9 = fexp2(x[9] - mx);
    float ea = fexp2(x[10] - mx), eb = fexp2(x[11] - mx);
    float ec = fexp2(x[12] - mx), ed = fexp2(x[13] - mx);
    float ee = fexp2(x[14] - mx), ef = fexp2(x[15] - mx);
    e0 += e8; e1 += e9; e2 += ea; e3 += eb; e4 += ec; e5 += ed; e6 += ee; e7 += ef;
    e0 += e4; e1 += e5; e2 += e6; e3 += e7;
    e0 += e2; e1 += e3;
    return e0 + e1;
}

// ---------------------------------------------------------------------------
// K12: wave-synchronous scans, base-2 domain, unroll-2 ping-pong panels
// (true prefetch distance 2, no register rotation, no barriers).
// ---------------------------------------------------------------------------
#define FWD_LOAD(P, tt) do {                                                   \
    const float* _b = phiN + (size_t)((tt) * NB + n) * 1024;                   \
    _Pragma("unroll")                                                          \
    for (int m = 0; m < 16; ++m) P[m] = _b[(half * 16 + m) * 32 + jl];         \
} while (0)

#define BWD_LOAD(P, tt) do {                                                   \
    const float4* _nb = (const float4*)(phiN + (size_t)((tt) * NB + n) * 1024  \
                                        + (size_t)jl * 32 + half * 16);        \
    float4 _a = _nb[0], _b4 = _nb[1], _c4 = _nb[2], _d4 = _nb[3];              \
    P[0]=_a.x;  P[1]=_a.y;  P[2]=_a.z;  P[3]=_a.w;                             \
    P[4]=_b4.x; P[5]=_b4.y; P[6]=_b4.z; P[7]=_b4.w;                            \
    P[8]=_c4.x; P[9]=_c4.y; P[10]=_c4.z; P[11]=_c4.w;                          \
    P[12]=_d4.x; P[13]=_d4.y; P[14]=_d4.z; P[15]=_d4.w;                        \
} while (0)

#define SCAN_CORE(P, OUTARR, tcur, PREFETCH)                                   \
    do {                                                                       \
        float x[16];                                                           \
        _Pragma("unroll")                                                      \
        for (int m = 0; m < 16; ++m) x[m] = P[m] + carr[m];                    \
        PREFETCH;                                                              \
        float mx = tree_max16(x);                                              \
        float s = tree_sum_exp2_16(x, mx);                                     \
        float mo = __shfl_xor(mx, 32);                                         \
        float so = __shfl_xor(s, 32);                                          \
        float M = fmaxf(mx, mo);                                               \
        s = s * fexp2(mx - M) + so * fexp2(mo - M);                            \
        float nv = M + flog2(s);                                               \
        if (lane < 32) OUTARR[((size_t)(tcur) * NB + n) * SPW + jl] = cj;      \
        cj = nv;                                                               \
        _Pragma("unroll")                                                      \
        for (int m = 0; m < 16; ++m) carr[m] = __shfl(nv, half * 16 + m);      \
    } while (0)

__global__ __launch_bounds__(64) void scan_kernel(
    const float* __restrict__ phiN, float* __restrict__ alphas_pre,
    float* __restrict__ betas_next, float* __restrict__ logZ, float* __restrict__ out)
{
    bool bwd = blockIdx.x >= NB;
    int n = blockIdx.x & (NB - 1);
    int lane = threadIdx.x;
    int half = lane >> 5;
    int jl = lane & 31;
    float carr[16];
#pragma unroll
    for (int m = 0; m < 16; ++m) carr[m] = 0.f;
    float cj = 0.f;
    float pA[16], pB[16];

    if (!bwd) {
        FWD_LOAD(pA, 0);
        FWD_LOAD(pB, 1);
        for (int it = 0; it < TT - 2; it += 2) {
            SCAN_CORE(pA, alphas_pre, it,
                      if (it + 2 < TT - 1) FWD_LOAD(pA, it + 2));
            SCAN_CORE(pB, alphas_pre, it + 1,
                      if (it + 3 < TT - 1) FWD_LOAD(pB, it + 3));
        }
        SCAN_CORE(pA, alphas_pre, TT - 2, );
        // logZ + log_softmax(alpha_T); convert to natural at the boundary
        float mx = cj;
#pragma unroll
        for (int off = 16; off; off >>= 1) mx = fmaxf(mx, __shfl_xor(mx, off));
        float s = fexp2(cj - mx);
#pragma unroll
        for (int off = 16; off; off >>= 1) s += __shfl_xor(s, off);
        float lg = flog2(s);
        if (lane == 0) {
            logZ[n] = (mx + lg) * LN2;       // natural
            logZ[32 + n] = mx + lg;          // base-2 (for elbo)
        }
        if (lane < 32) out[2 + n * 32 + jl] = (cj - mx - lg) * LN2;
    } else {
        BWD_LOAD(pA, TT - 2);
        BWD_LOAD(pB, TT - 3);
        for (int it = TT - 2; it >= 2; it -= 2) {
            SCAN_CORE(pA, betas_next, it,
                      if (it - 2 >= 0) BWD_LOAD(pA, it - 2));
            SCAN_CORE(pB, betas_next, it - 1,
                      if (it - 3 >= 0) BWD_LOAD(pB, it - 3));
        }
        SCAN_CORE(pA, betas_next, 0, );
    }
}

// ---------------------------------------------------------------------------
// K13: elbo (base-2) with private partials + fused finalize (done counter).
// ---------------------------------------------------------------------------
__global__ __launch_bounds__(256) void elbo_fin_kernel(
    const float* __restrict__ phiN, const float* __restrict__ alphas_pre,
    const float* __restrict__ betas_next, const float* __restrict__ logZ,
    double* __restrict__ epart, unsigned* __restrict__ done, float* __restrict__ out)
{
    int t = blockIdx.x / NB;
    int n = blockIdx.x - t * NB;
    int tid = threadIdx.x;
    __shared__ float ap[32], bn[32];
    __shared__ int amLast;
    if (tid < 32) ap[tid] = alphas_pre[((size_t)t * NB + n) * SPW + tid];
    else if (tid < 64) bn[tid - 32] = betas_next[((size_t)t * NB + n) * SPW + (tid - 32)];
    __syncthreads();
    float lz2 = logZ[32 + n];
    size_t base = (size_t)(t * NB + n) * 1024;
    double local = 0.0;
#pragma unroll
    for (int e = tid; e < 1024; e += 256) {
        int i = e >> 5, j = e & 31;
        float ph2 = phiN[base + e];
        float lm2 = ap[i] + ph2 + bn[j] - lz2;
        local += (double)(fexp2(lm2) * (ph2 * LN2));
    }
#pragma unroll
    for (int off = 32; off; off >>= 1) local += __shfl_down(local, off);
    __shared__ double wsum[4];
    if ((tid & 63) == 0) wsum[tid >> 6] = local;
    __syncthreads();
    if (tid == 0) {
        epart[blockIdx.x] = wsum[0] + wsum[1] + wsum[2] + wsum[3];
        __threadfence();
        amLast = (atomicAdd(done, 1u) == (unsigned)(NTOK - 1));
    }
    __syncthreads();
    if (amLast) {
        double lsum = 0.0;
        for (int i = tid; i < NTOK; i += 256)
            lsum += atomicAdd(&epart[i], 0.0);   // device-scope coherent read
#pragma unroll
        for (int off = 32; off; off >>= 1) lsum += __shfl_down(lsum, off);
        __shared__ double fsum[4];
        if ((tid & 63) == 0) fsum[tid >> 6] = lsum;
        __syncthreads();
        if (tid == 0) {
            out[0] = (float)(fsum[0] + fsum[1] + fsum[2] + fsum[3]);
            float s = 0.f;
            for (int k = 0; k < NB; ++k) s += logZ[k];
            out[1] = s;
        }
    }
}

// ---------------------------------------------------------------------------
extern "C" void kernel_launch(void* const* d_in, const int* in_sizes, int n_in,
                              void* d_out, int out_size, void* d_ws, size_t ws_size,
                              hipStream_t stream) {
    (void)in_sizes; (void)n_in; (void)out_size; (void)ws_size;
    const float* start_emb = (const float*)d_in[0];
    const float* sw1  = (const float*)d_in[1];
    const float* sb1  = (const float*)d_in[2];
    const float* sw2  = (const float*)d_in[3];
    const float* sb2  = (const float*)d_in[4];
    const float* sow  = (const float*)d_in[5];
    const float* state_emb = (const float*)d_in[7];
    const float* tw1  = (const float*)d_in[8];
    const float* tb1  = (const float*)d_in[9];
    const float* tw2  = (const float*)d_in[10];
    const float* tb2  = (const float*)d_in[11];
    const float* nsp  = (const float*)d_in[12];
    const float* pre_emb = (const float*)d_in[13];
    const float* ew1  = (const float*)d_in[14];
    const float* eb1  = (const float*)d_in[15];
    const float* ew2  = (const float*)d_in[16];
    const float* eb2  = (const float*)d_in[17];
    const float* eow  = (const float*)d_in[18];
    const float* eob  = (const float*)d_in[19];
    const int*   text = (const int*)d_in[20];
    const int*   w2s  = (const int*)d_in[21];

    float* ws = (float*)d_ws;
    float* TL      = ws + OFF_TL;
    float* s_tmp   = ws + OFF_STMP;
    float* startl  = ws + OFF_START;
    float* lse1    = ws + OFF_LSE1;
    unsigned* rmax = (unsigned*)(ws + OFF_RMAX);
    float* rsum    = ws + OFF_RSUM;
    float* den     = ws + OFF_DEN;
    float* logZ    = ws + OFF_LOGZ;
    unsigned* done = (unsigned*)(ws + OFF_ELBO);
    float2* part   = (float2*)(ws + OFF_PART);
    double* epart  = (double*)(ws + OFF_EPART);
    unsigned short* Xp  = (unsigned short*)(ws + OFF_XP);
    unsigned short* Hp  = (unsigned short*)(ws + OFF_HP);
    unsigned short* W1p = (unsigned short*)(ws + OFF_W1P);
    unsigned short* W2p = (unsigned short*)(ws + OFF_W2P);
    unsigned short* Ap  = (unsigned short*)(ws + OFF_AP);
    unsigned short* Bp  = (unsigned short*)(ws + OFF_BP);
    float* ewT     = ws + OFF_EWT;
    float* Lm      = ws + OFF_L;
    float* phiN    = ws + OFF_PHI;
    float* res_e   = ws + OFF_RES_E;
    float* alph    = ws + OFF_ALPH;
    float* beta    = ws + OFF_BETA;
    int* cnt       = (int*)(ws + OFF_CNT);
    int* offs      = (int*)(ws + OFF_OFFS);
    int* cur       = (int*)(ws + OFF_CUR);
    int* ent       = (int*)(ws + OFF_ENT);
    float* out     = (float*)d_out;

    // pack inputs/weights (+ fused accumulator/done init); MLPs on MFMA
    pack_all_kernel<<<4496, 256, 0, stream>>>(start_emb, state_emb, pre_emb, nsp,
                                              sw1, tw1, ew1, sw2, tw2, ew2,
                                              Xp, Bp, W1p, W2p,
                                              rmax, rsum, cnt, s_tmp, done);
    gemm_layer1<<<dim3(2, 96), 256, 0, stream>>>(Xp, W1p, sb1, tb1, eb1, Hp);
    gemm_layer2<<<dim3(2, 96), 256, 0, stream>>>(Hp, W2p, sb2, tb2, eb2,
                                                 start_emb, state_emb, pre_emb,
                                                 sow, s_tmp, Ap, res_e);

    // transition path: TL GEMM with contention-free lse partials
    gemm_bt_kernel<<<dim3(32, 32), 256, 0, stream>>>(Ap, Bp, TL, part);

    // emission path (Ap/Bp dead now; ewT overwrites them)
    transpose_kernel<<<dim3(V_ / 32, H_ / 32), 256, 0, stream>>>(eow, ewT);
    em_logits_kernel<<<V_, 256, 0, stream>>>(res_e, ewT, eob, w2s, Lm, rmax);
    row_sum_kernel<<<V_ / 8, 256, 0, stream>>>(w2s, Lm, rmax, rsum);
    denom_hist_lse_kernel<<<16 + NITEM / 256 + 1024 + 1, 256, 0, stream>>>(
        rmax, rsum, den, text, w2s, cnt, part, lse1, s_tmp, startl);
    prefix_kernel<<<1, 1024, 0, stream>>>(cnt, offs, cur);
    fill_kernel<<<NITEM / 256, 256, 0, stream>>>(text, w2s, cur, ent);

    // phi assembly (obs inline, base-2 scaled) + scans + outputs
    phi_gather_kernel<<<C_, 256, 0, stream>>>(TL, offs, ent, lse1, startl,
                                              Lm, den, text, w2s, phiN);
    scan_kernel<<<2 * NB, 64, 0, stream>>>(phiN, alph, beta, logZ, out);
    elbo_fin_kernel<<<NTOK, 256, 0, stream>>>(phiN, alph, beta, logZ, epart, done, out);
}

// Round 13
// 445.835 us; speedup vs baseline: 1.1631x; 1.1631x over previous
//
#include <hip/hip_runtime.h>
#include <hip/hip_fp16.h>
#include <math.h>

// Problem constants (fixed by the reference)
#define C_   4096
#define H_   256
#define V_   16000
#define SPW  32
#define NB   32    // N (batch)
#define TT   128   // T (sequence length)
#define NTOK ((TT - 1) * NB)          // 4064 token transitions
#define NITEM (NTOK * SPW)            // 130048 (nt, i) row-uses
#define GEMM_K 768                    // 3 x 256 split-fp16 segments
#define LOG2E 1.44269504088896340736f
#define LN2   0.69314718055994530942f

// raw hardware transcendentals (v_exp_f32 computes 2^x, v_log_f32 is log2).
__device__ inline float fexp2(float x) { return __builtin_amdgcn_exp2f(x); }
__device__ inline float flog2(float x) { return __builtin_amdgcn_logf(x); }

// ---------------------------------------------------------------------------
// Workspace layout (float offsets). Total ~27.0M floats = ~108 MB.
// ---------------------------------------------------------------------------
static const size_t OFF_TL    = 0;                                   // C*C transition logits
static const size_t OFF_RES   = OFF_TL   + (size_t)C_ * C_;          // C*H spare: lse partials (4 MB exact)
static const size_t OFF_STMP  = OFF_RES  + (size_t)C_ * H_;          // C   start pre-softmax
static const size_t OFF_START = OFF_STMP + C_;                       // C   start log-probs
static const size_t OFF_LSE1  = OFF_START + C_;                      // C
static const size_t OFF_LSE2  = OFF_LSE1 + C_;                       // C (spare)
static const size_t OFF_RMAX  = OFF_LSE2 + C_;                       // C (unsigned, encoded-float max)
static const size_t OFF_RSUM  = OFF_RMAX + C_;                       // C
static const size_t OFF_DEN   = OFF_RSUM + C_;                       // C emission row log-denominator
static const size_t OFF_LOGZ  = OFF_DEN  + C_;                       // [0,32) natural; [32,64) base-2
static const size_t OFF_ELBO  = OFF_LOGZ + 64;                       // (spare)
static const size_t OFF_EWT   = OFF_ELBO + 16;                       // V*H region (Ap/Bp early, ewT later)
static const size_t OFF_L     = OFF_EWT  + (size_t)V_ * H_;          // V*SPW masked emission logits
static const size_t OFF_OBS   = OFF_L    + (size_t)V_ * SPW;         // elbo partials (obs deleted)
static const size_t OFF_PHI   = OFF_OBS  + (size_t)NB * TT * SPW;    // phiN[t,n,i,j] * LOG2E (base-2)
static const size_t OFF_ALPH  = OFF_PHI  + (size_t)NTOK * SPW * SPW; // (T-1)*N*SPW (base-2)
static const size_t OFF_BETA  = OFF_ALPH + (size_t)NTOK * SPW;       // (T-1)*N*SPW (base-2)

// lse partials: part[row][slice], 4096 x 128 float2 = 1,048,576 floats (exact RES fit)
static const size_t OFF_PART  = OFF_RES;
// elbo per-block partials: NTOK doubles in the freed obs region (8B aligned)
static const size_t OFF_EPART = OFF_OBS;

// MLP GEMM scratch aliased onto TL region (dead until gemm_bt writes TL):
static const size_t OFF_XP    = OFF_TL;                                   // 12288x768 us
static const size_t OFF_HP    = OFF_TL + (size_t)3 * C_ * GEMM_K / 2;     // 12288x768 us
static const size_t OFF_W1P   = OFF_TL + (size_t)6 * C_ * GEMM_K / 2;     // 3 x 256x768 us
static const size_t OFF_W2P   = OFF_W1P + (size_t)3 * 256 * GEMM_K / 2;

// Ap/Bp (TL-GEMM operands) in the ewT region; ewT overwrites them after gemm_bt.
static const size_t OFF_AP    = OFF_EWT;                              // 4096x768 us
static const size_t OFF_BP    = OFF_EWT + (size_t)C_ * GEMM_K / 2;    // 4096x768 us

// res_e aliased onto phi region (phi written much later by phi_gather).
static const size_t OFF_RES_E = OFF_PHI + (size_t)C_ * H_;

// Inverted-index scratch aliased onto alpha/beta region (dead until scan).
static const size_t OFF_CNT   = OFF_ALPH;            // 4096 int
static const size_t OFF_OFFS  = OFF_ALPH + 4096;     // 4097 int (pad to 4112)
static const size_t OFF_CUR   = OFF_ALPH + 8208;     // 4096 int
static const size_t OFF_ENT   = OFF_ALPH + 12304;    // NITEM int

// Monotone float<->uint encoding for atomicMax on floats (handles negatives)
__device__ inline unsigned enc_f(float f) {
    unsigned u = __float_as_uint(f);
    return (u & 0x80000000u) ? ~u : (u | 0x80000000u);
}
__device__ inline float dec_f(unsigned k) {
    return (k & 0x80000000u) ? __uint_as_float(k ^ 0x80000000u) : __uint_as_float(~k);
}

__device__ inline void split_h(float v, unsigned short& hi, unsigned short& lo) {
    __half h = __float2half(v);
    __half l = __float2half(v - __half2float(h));
    __builtin_memcpy(&hi, &h, 2);
    __builtin_memcpy(&lo, &l, 2);
}

typedef __attribute__((ext_vector_type(8))) short short8;
typedef __attribute__((ext_vector_type(4))) float floatx4;

#define GLB(p)  ((const __attribute__((address_space(1))) unsigned int*)(p))
#define LDSP(p) ((__attribute__((address_space(3))) unsigned int*)(p))

// ---------------------------------------------------------------------------
// K1: pack everything to split-fp16; trailing 16 blocks do accumulator init.
// ---------------------------------------------------------------------------
__global__ __launch_bounds__(256) void pack_all_kernel(
    const float* __restrict__ se, const float* __restrict__ ste, const float* __restrict__ pe,
    const float* __restrict__ nsp,
    const float* __restrict__ w1_0, const float* __restrict__ w1_1, const float* __restrict__ w1_2,
    const float* __restrict__ w2_0, const float* __restrict__ w2_1, const float* __restrict__ w2_2,
    unsigned short* __restrict__ Xp, unsigned short* __restrict__ Bp,
    unsigned short* __restrict__ W1p, unsigned short* __restrict__ W2p,
    unsigned* __restrict__ rowmax, float* __restrict__ rowsum,
    int* __restrict__ cnt, float* __restrict__ s_tmp)
{
    __shared__ float tile_s[32][33];
    int blk = blockIdx.x;
    if (blk < 4096) {
        bool isB = blk >= 3072;
        int e4 = (isB ? blk - 3072 : blk) * 256 + threadIdx.x;
        int r = e4 >> 6;
        int c = (e4 & 63) * 4;
        const float* src;
        unsigned short* dst;
        if (isB) { src = nsp + (size_t)r * H_; dst = Bp; }
        else {
            int inst = r >> 12;
            int rl = r & 4095;
            src = (inst == 0 ? se : inst == 1 ? ste : pe) + (size_t)rl * H_;
            dst = Xp;
        }
        float4 v = *(const float4*)(src + c);
        float vv[4] = {v.x, v.y, v.z, v.w};
        union { unsigned short s[4]; ushort4 u; } hi, lo;
#pragma unroll
        for (int q = 0; q < 4; ++q) split_h(vv[q], hi.s[q], lo.s[q]);
        size_t base = (size_t)r * GEMM_K + c;
        if (!isB) {   // A-layout [hi | lo | hi]
            *(ushort4*)&dst[base]       = hi.u;
            *(ushort4*)&dst[base + 256] = lo.u;
            *(ushort4*)&dst[base + 512] = hi.u;
        } else {      // B-layout [hi | hi | lo]
            *(ushort4*)&dst[base]       = hi.u;
            *(ushort4*)&dst[base + 256] = hi.u;
            *(ushort4*)&dst[base + 512] = lo.u;
        }
    } else if (blk < 4480) {
        int b = blk - 4096;
        int mat = b >> 6, tile = b & 63;
        int n0 = (tile & 7) * 32, k0 = (tile >> 3) * 32;
        const float* W = mat == 0 ? w1_0 : mat == 1 ? w1_1 : mat == 2 ? w1_2
                       : mat == 3 ? w2_0 : mat == 4 ? w2_1 : w2_2;
        unsigned short* dst = (mat < 3) ? W1p + (size_t)mat * 256 * GEMM_K
                                        : W2p + (size_t)(mat - 3) * 256 * GEMM_K;
        int tx = threadIdx.x & 31, ty = threadIdx.x >> 5;
#pragma unroll
        for (int q = 0; q < 4; ++q)
            tile_s[ty + 8 * q][tx] = W[(size_t)(k0 + ty + 8 * q) * 256 + n0 + tx];
        __syncthreads();
#pragma unroll
        for (int q = 0; q < 4; ++q) {
            float v = tile_s[tx][ty + 8 * q];
            unsigned short hi, lo;
            split_h(v, hi, lo);
            size_t ob = (size_t)(n0 + ty + 8 * q) * GEMM_K + k0 + tx;
            dst[ob] = hi; dst[ob + 256] = hi; dst[ob + 512] = lo;
        }
    } else {
        int i = (blk - 4480) * 256 + threadIdx.x;   // < 4096
        rowmax[i] = 0u; rowsum[i] = 0.f; cnt[i] = 0; s_tmp[i] = 0.f;
    }
}

// ---------------------------------------------------------------------------
// Shared GEMM core: 128x128 tile, 4 waves of 64x64, f16 16x16x32 MFMA, K=768.
// ---------------------------------------------------------------------------
#define GEMM_PROLOGUE(APTR, BPTR)                                              \
    __shared__ __align__(16) unsigned short As[128 * 64];                      \
    __shared__ __align__(16) unsigned short Bs[128 * 64];                      \
    int tid = threadIdx.x;                                                     \
    int wave = tid >> 6, lane = tid & 63;                                      \
    int wm = (wave & 1) * 64, wn = (wave >> 1) * 64;                           \
    int l15 = lane & 15, quad = lane >> 4;                                     \
    floatx4 acc[4][4] = {};                                                    \
    int c0row = tid >> 3;                                                      \
    int c0col = (tid & 7) * 8;                                                 \
    for (int k0 = 0; k0 < GEMM_K; k0 += 64) {                                  \
        __syncthreads();                                                       \
        _Pragma("unroll")                                                      \
        for (int q = 0; q < 4; ++q) {                                          \
            int row = c0row + q * 32;                                          \
            const unsigned short* ga = (APTR) + (size_t)(i0 + row) * GEMM_K + k0 + c0col; \
            const unsigned short* gb = (BPTR) + (size_t)(j0 + row) * GEMM_K + k0 + c0col; \
            __builtin_amdgcn_global_load_lds(GLB(ga), LDSP(&As[(size_t)row * 64 + c0col]), 16, 0, 0); \
            __builtin_amdgcn_global_load_lds(GLB(gb), LDSP(&Bs[(size_t)row * 64 + c0col]), 16, 0, 0); \
        }                                                                      \
        __syncthreads();                                                       \
        _Pragma("unroll")                                                      \
        for (int ks = 0; ks < 64; ks += 32) {                                  \
            short8 af[4], bfr[4];                                              \
            _Pragma("unroll")                                                  \
            for (int mi = 0; mi < 4; ++mi)                                     \
                af[mi] = *(const short8*)&As[(wm + mi * 16 + l15) * 64 + ks + quad * 8]; \
            _Pragma("unroll")                                                  \
            for (int ni = 0; ni < 4; ++ni)                                     \
                bfr[ni] = *(const short8*)&Bs[(wn + ni * 16 + l15) * 64 + ks + quad * 8]; \
            _Pragma("unroll")                                                  \
            for (int mi = 0; mi < 4; ++mi)                                     \
                _Pragma("unroll")                                              \
                for (int ni = 0; ni < 4; ++ni)                                 \
                    acc[mi][ni] = __builtin_amdgcn_mfma_f32_16x16x32_f16(      \
                        af[mi], bfr[ni], acc[mi][ni], 0, 0, 0);                \
        }                                                                      \
    }

// ---------------------------------------------------------------------------
// K2: MLP layer 1: H = relu(X@W1 + b1), packed split-fp16 out (A-layout).
// ---------------------------------------------------------------------------
__global__ __launch_bounds__(256) void gemm_layer1(
    const unsigned short* __restrict__ Xp, const unsigned short* __restrict__ Wp,
    const float* __restrict__ b0, const float* __restrict__ b1, const float* __restrict__ b2,
    unsigned short* __restrict__ Hp)
{
    int i0 = blockIdx.y * 128, j0 = blockIdx.x * 128;
    int inst = blockIdx.y >> 5;
    const unsigned short* Wbase = Wp + (size_t)inst * 256 * GEMM_K;
    const float* bias = inst == 0 ? b0 : (inst == 1 ? b1 : b2);
    GEMM_PROLOGUE(Xp, Wbase)
#pragma unroll
    for (int mi = 0; mi < 4; ++mi) {
#pragma unroll
        for (int reg = 0; reg < 4; ++reg) {
            int row = i0 + wm + mi * 16 + quad * 4 + reg;
#pragma unroll
            for (int ni = 0; ni < 4; ++ni) {
                int col = j0 + wn + ni * 16 + l15;
                float h = fmaxf(acc[mi][ni][reg] + bias[col], 0.f);
                unsigned short hi, lo;
                split_h(h, hi, lo);
                size_t base = (size_t)row * GEMM_K + col;
                Hp[base] = hi; Hp[base + 256] = lo; Hp[base + 512] = hi;
            }
        }
    }
}

// ---------------------------------------------------------------------------
// K3: MLP layer 2: Z = relu(H@W2 + b2) + X, per-instance epilogue.
// ---------------------------------------------------------------------------
__global__ __launch_bounds__(256) void gemm_layer2(
    const unsigned short* __restrict__ Hp, const unsigned short* __restrict__ Wp,
    const float* __restrict__ b0, const float* __restrict__ b1, const float* __restrict__ b2,
    const float* __restrict__ x0, const float* __restrict__ x1, const float* __restrict__ x2,
    const float* __restrict__ sow, float* __restrict__ s_tmp,
    unsigned short* __restrict__ Ap, float* __restrict__ res_e)
{
    int i0 = blockIdx.y * 128, j0 = blockIdx.x * 128;
    int inst = blockIdx.y >> 5;
    const unsigned short* Wbase = Wp + (size_t)inst * 256 * GEMM_K;
    const float* bias = inst == 0 ? b0 : (inst == 1 ? b1 : b2);
    const float* X = inst == 0 ? x0 : (inst == 1 ? x1 : x2);
    GEMM_PROLOGUE(Hp, Wbase)
#pragma unroll
    for (int mi = 0; mi < 4; ++mi) {
#pragma unroll
        for (int reg = 0; reg < 4; ++reg) {
            int row = i0 + wm + mi * 16 + quad * 4 + reg;
            int rl = row & 4095;
            float ps = 0.f;
#pragma unroll
            for (int ni = 0; ni < 4; ++ni) {
                int col = j0 + wn + ni * 16 + l15;
                float z = fmaxf(acc[mi][ni][reg] + bias[col], 0.f)
                        + X[(size_t)rl * H_ + col];
                if (inst == 0) {
                    ps += z * sow[col];
                } else if (inst == 1) {
                    unsigned short hi, lo;
                    split_h(z, hi, lo);
                    size_t base = (size_t)rl * GEMM_K + col;
                    Ap[base] = hi; Ap[base + 256] = lo; Ap[base + 512] = hi;
                } else {
                    res_e[(size_t)rl * H_ + col] = z;
                }
            }
            if (inst == 0) {
                ps += __shfl_xor(ps, 1);
                ps += __shfl_xor(ps, 2);
                ps += __shfl_xor(ps, 4);
                ps += __shfl_xor(ps, 8);
                if (l15 == 0) atomicAdd(&s_tmp[rl], ps);
            }
        }
    }
}

// ---------------------------------------------------------------------------
// K4: TL = Ap.Bp^T with per-row lse partials: 3 shuffle-merge levels only,
// 2 partials per 16-lane group -> part[row][128 slices].  No atomics.
// ---------------------------------------------------------------------------
__global__ __launch_bounds__(256) void gemm_bt_kernel(
    const unsigned short* __restrict__ Ap, const unsigned short* __restrict__ Bp,
    float* __restrict__ Cmat, float2* __restrict__ part)
{
    int i0 = blockIdx.y * 128, j0 = blockIdx.x * 128;
    GEMM_PROLOGUE(Ap, Bp)
    int slice = (blockIdx.x * 2 + (wave >> 1)) * 2;
#pragma unroll
    for (int mi = 0; mi < 4; ++mi) {
#pragma unroll
        for (int reg = 0; reg < 4; ++reg) {
            int row = i0 + wm + mi * 16 + quad * 4 + reg;
            float* crow = Cmat + (size_t)row * C_ + j0 + wn;
#pragma unroll
            for (int ni = 0; ni < 4; ++ni)
                crow[ni * 16 + l15] = acc[mi][ni][reg];
            float m = fmaxf(fmaxf(acc[mi][0][reg], acc[mi][1][reg]),
                            fmaxf(acc[mi][2][reg], acc[mi][3][reg]));
            float s = __expf(acc[mi][0][reg] - m) + __expf(acc[mi][1][reg] - m)
                    + __expf(acc[mi][2][reg] - m) + __expf(acc[mi][3][reg] - m);
#pragma unroll
            for (int off = 1; off <= 4; off <<= 1) {
                float mo = __shfl_xor(m, off);
                float so = __shfl_xor(s, off);
                float M = fmaxf(m, mo);
                s = s * __expf(m - M) + so * __expf(mo - M);
                m = M;
            }
            if ((l15 & 7) == 0)
                part[(size_t)row * 128 + slice + (l15 >> 3)] = make_float2(m, s);
        }
    }
}

// ---------------------------------------------------------------------------
// K5: transpose e_out_w (H,V) -> ewT (V,H)  (overwrites dead Ap/Bp region)
// ---------------------------------------------------------------------------
__global__ __launch_bounds__(256) void transpose_kernel(
    const float* __restrict__ W, float* __restrict__ WT)
{
    __shared__ float tile[32][33];
    int tx = threadIdx.x & 31, ty = threadIdx.x >> 5;
    int v0 = blockIdx.x * 32, h0 = blockIdx.y * 32;
#pragma unroll
    for (int q = 0; q < 4; ++q)
        tile[ty + 8 * q][tx] = W[(size_t)(h0 + ty + 8 * q) * V_ + v0 + tx];
    __syncthreads();
#pragma unroll
    for (int q = 0; q < 4; ++q)
        WT[(size_t)(v0 + ty + 8 * q) * H_ + h0 + tx] = tile[tx][ty + 8 * q];
}

// ---------------------------------------------------------------------------
// K6: masked emission logits + FUSED per-state rowmax scatter (deduped).
// ---------------------------------------------------------------------------
__global__ __launch_bounds__(256) void em_logits_kernel(
    const float* __restrict__ res_pre, const float* __restrict__ ewT,
    const float* __restrict__ eob, const int* __restrict__ w2s,
    float* __restrict__ L, unsigned* __restrict__ rowmax)
{
    int v = blockIdx.x;
    __shared__ __align__(16) float wv[H_];
    __shared__ int st[32];
    wv[threadIdx.x] = ewT[(size_t)v * H_ + threadIdx.x];
    int g = threadIdx.x >> 3;
    int l = threadIdx.x & 7;
    int c = w2s[v * SPW + g];
    if (l == 0) st[g] = c;
    __syncthreads();
    const float4* row4 = (const float4*)(res_pre + (size_t)c * H_);
    const float4* wv4 = (const float4*)wv;
    float sum = 0.f;
#pragma unroll
    for (int m = 0; m < 8; ++m) {
        float4 r = row4[l + m * 8];
        float4 w = wv4[l + m * 8];
        sum += r.x * w.x + r.y * w.y + r.z * w.z + r.w * w.w;
    }
    sum += __shfl_xor(sum, 1);
    sum += __shfl_xor(sum, 2);
    sum += __shfl_xor(sum, 4);
    if (l == 0) {
        float logit = sum + eob[v];
        L[v * SPW + g] = logit;
        bool dup = false;
        for (int kp = 0; kp < g; ++kp) if (st[kp] == c) { dup = true; break; }
        if (!dup) atomicMax(&rowmax[c], enc_f(logit));
    }
}

// ---------------------------------------------------------------------------
// K7: scatter per-state sum(exp(x-max)), deduping repeated states
// ---------------------------------------------------------------------------
__global__ __launch_bounds__(256) void row_sum_kernel(
    const int* __restrict__ w2s, const float* __restrict__ L,
    const unsigned* __restrict__ rowmax, float* __restrict__ rowsum)
{
    __shared__ int st[8][32];
    int vl = threadIdx.x >> 5, k = threadIdx.x & 31;
    int v = blockIdx.x * 8 + vl;
    st[vl][k] = w2s[v * SPW + k];
    __syncthreads();
    int c = st[vl][k];
    bool dup = false;
    for (int kp = 0; kp < k; ++kp) if (st[vl][kp] == c) { dup = true; break; }
    if (!dup) atomicAdd(&rowsum[c], expf(L[v * SPW + k] - dec_f(rowmax[c])));
}

// ---------------------------------------------------------------------------
// K8: fused: denom (blocks 0..15) + hist (16..523) + lse1 fold (one wave per
// row, 128 partials each: 524..1547) + start log_softmax (block 1548).
// ---------------------------------------------------------------------------
__global__ __launch_bounds__(256) void denom_hist_lse_kernel(
    const unsigned* __restrict__ rowmax, const float* __restrict__ rowsum,
    float* __restrict__ denom, const int* __restrict__ text,
    const int* __restrict__ w2s, int* __restrict__ count,
    const float2* __restrict__ part, float* __restrict__ lse1,
    const float* __restrict__ s_tmp, float* __restrict__ startl)
{
    int blk = blockIdx.x;
    if (blk < 16) {
        int c = blk * 256 + threadIdx.x;
        unsigned k = rowmax[c];
        denom[c] = (k == 0u) ? -INFINITY : (dec_f(k) + logf(rowsum[c]));
    } else if (blk < 16 + NITEM / 256) {
        int item = (blk - 16) * 256 + threadIdx.x;
        int i  = item & 31;
        int nt = item >> 5;
        int t = nt >> 5, n = nt & 31;
        int v0 = text[n * TT + t];
        int ci = w2s[v0 * SPW + i];
        atomicAdd(&count[ci], 1);
    } else if (blk < 16 + NITEM / 256 + 1024) {
        int row = (blk - 16 - NITEM / 256) * 4 + (threadIdx.x >> 6);
        int lane = threadIdx.x & 63;
        const float2* pr = part + (size_t)row * 128;
        float2 p0 = pr[lane];
        float2 p1 = pr[64 + lane];
        float m = fmaxf(p0.x, p1.x);
        float s = p0.y * __expf(p0.x - m) + p1.y * __expf(p1.x - m);
#pragma unroll
        for (int off = 1; off <= 32; off <<= 1) {
            float mo = __shfl_xor(m, off);
            float so = __shfl_xor(s, off);
            float M = fmaxf(m, mo);
            s = s * __expf(m - M) + so * __expf(mo - M);
            m = M;
        }
        if (lane == 0) lse1[row] = m + logf(s);
    } else {
        __shared__ float red_m[4];
        __shared__ float red_s[4];
        int t = threadIdx.x;
        float v[16];
        float mx = -INFINITY;
#pragma unroll
        for (int q = 0; q < 16; ++q) { v[q] = s_tmp[t + q * 256]; mx = fmaxf(mx, v[q]); }
#pragma unroll
        for (int off = 32; off; off >>= 1) mx = fmaxf(mx, __shfl_xor(mx, off));
        if ((t & 63) == 0) red_m[t >> 6] = mx;
        __syncthreads();
        float M = fmaxf(fmaxf(red_m[0], red_m[1]), fmaxf(red_m[2], red_m[3]));
        float sm = 0.f;
#pragma unroll
        for (int q = 0; q < 16; ++q) sm += __expf(v[q] - M);
#pragma unroll
        for (int off = 32; off; off >>= 1) sm += __shfl_xor(sm, off);
        if ((t & 63) == 0) red_s[t >> 6] = sm;
        __syncthreads();
        float S = red_s[0] + red_s[1] + red_s[2] + red_s[3];
        float lg = logf(S);
#pragma unroll
        for (int q = 0; q < 16; ++q) startl[t + q * 256] = (v[q] - M) - lg;
    }
}

// ---------------------------------------------------------------------------
// K9: single-block 1024-thread prefix scan of counts.
// ---------------------------------------------------------------------------
__global__ __launch_bounds__(1024) void prefix_kernel(
    const int* __restrict__ count, int* __restrict__ offs, int* __restrict__ cursor)
{
    __shared__ int buf[1024];
    int t = threadIdx.x;
    int c0 = count[t * 4 + 0], c1 = count[t * 4 + 1];
    int c2 = count[t * 4 + 2], c3 = count[t * 4 + 3];
    int s = c0 + c1 + c2 + c3;
    buf[t] = s;
    __syncthreads();
    for (int d = 1; d < 1024; d <<= 1) {
        int v = (t >= d) ? buf[t - d] : 0;
        __syncthreads();
        buf[t] += v;
        __syncthreads();
    }
    int excl = buf[t] - s;
    offs[t * 4 + 0] = excl; cursor[t * 4 + 0] = excl; excl += c0;
    offs[t * 4 + 1] = excl; cursor[t * 4 + 1] = excl; excl += c1;
    offs[t * 4 + 2] = excl; cursor[t * 4 + 2] = excl; excl += c2;
    offs[t * 4 + 3] = excl; cursor[t * 4 + 3] = excl;
    if (t == 1023) offs[4096] = buf[1023];
}

// ---------------------------------------------------------------------------
// K10: index fill (obs computed inline in phi_gather)
// ---------------------------------------------------------------------------
__global__ void fill_kernel(const int* __restrict__ text, const int* __restrict__ w2s,
                            int* __restrict__ cursor, int* __restrict__ entries)
{
    int item = blockIdx.x * 256 + threadIdx.x;
    int i  = item & 31;
    int nt = item >> 5;
    int t = nt >> 5, n = nt & 31;
    int v0 = text[n * TT + t];
    int ci = w2s[v0 * SPW + i];
    int pos = atomicAdd(&cursor[ci], 1);
    entries[pos] = item;
}

// ---------------------------------------------------------------------------
// K11: phi gather, inverted, obs computed inline (Lm/den gathers, L1-served).
// phiN layout: [t, n, i, j] (j innermost), scaled by LOG2E (base-2 domain).
// ---------------------------------------------------------------------------
__global__ __launch_bounds__(256) void phi_gather_kernel(
    const float* __restrict__ TL, const int* __restrict__ offs, const int* __restrict__ entries,
    const float* __restrict__ lse1, const float* __restrict__ start_log,
    const float* __restrict__ Lm, const float* __restrict__ den,
    const int* __restrict__ text, const int* __restrict__ w2s, float* __restrict__ phiN)
{
    int ci = blockIdx.x;
    __shared__ float row[C_];   // 16 KB
    {
        const float4* src = (const float4*)(TL + (size_t)ci * C_);
        float4* dst = (float4*)row;
        for (int q = threadIdx.x; q < C_ / 4; q += 256) dst[q] = src[q];
    }
    __syncthreads();
    float abase = -lse1[ci];
    float st = start_log[ci];
    float dci = den[ci];
    int beg = offs[ci], end = offs[ci + 1];
    int g = threadIdx.x >> 5, lane = threadIdx.x & 31;
    for (int idx = beg + g; idx < end; idx += 8) {
        int item = entries[idx];
        int i  = item & 31;
        int nt = item >> 5;
        int t = nt >> 5, n = nt & 31;
        int v1 = text[n * TT + t + 1];
        int cj = w2s[v1 * SPW + lane];
        float ob = Lm[v1 * SPW + lane] - den[cj];
        float a = abase;
        if (t == 0) {
            int v0 = text[n * TT];
            a += st + (Lm[v0 * SPW + i] - dci);
        }
        phiN[(size_t)nt * 1024 + i * 32 + lane] = (row[cj] + a + ob) * LOG2E;
    }
}

// tree helpers over a 16-register panel (explicit log-depth reductions)
__device__ inline float tree_max16(const float* x) {
    float r0 = fmaxf(x[0], x[8]),  r1 = fmaxf(x[1], x[9]);
    float r2 = fmaxf(x[2], x[10]), r3 = fmaxf(x[3], x[11]);
    float r4 = fmaxf(x[4], x[12]), r5 = fmaxf(x[5], x[13]);
    float r6 = fmaxf(x[6], x[14]), r7 = fmaxf(x[7], x[15]);
    r0 = fmaxf(r0, r4); r1 = fmaxf(r1, r5); r2 = fmaxf(r2, r6); r3 = fmaxf(r3, r7);
    r0 = fmaxf(r0, r2); r1 = fmaxf(r1, r3);
    return fmaxf(r0, r1);
}
__device__ inline float tree_sum_exp2_16(const float* x, float mx) {
    float e0 = fexp2(x[0] - mx),  e1 = fexp2(x[1] - mx);
    float e2 = fexp2(x[2] - mx),  e3 = fexp2(x[3] - mx);
    float e4 = fexp2(x[4] - mx),  e5 = fexp2(x[5] - mx);
    float e6 = fexp2(x[6] - mx),  e7 = fexp2(x[7] - mx);
    float e8 = fexp2(x[8] - mx),  e9 = fexp2(x[9] - mx);
    float ea = fexp2(x[10] - mx), eb = fexp2(x[11] - mx);
    float ec = fexp2(x[12] - mx), ed = fexp2(x[13] - mx);
    float ee = fexp2(x[14] - mx), ef = fexp2(x[15] - mx);
    e0 += e8; e1 += e9; e2 += ea; e3 += eb; e4 += ec; e5 += ed; e6 += ee; e7 += ef;
    e0 += e4; e1 += e5; e2 += e6; e3 += e7;
    e0 += e2; e1 += e3;
    return e0 + e1;
}

// ---------------------------------------------------------------------------
// K12: wave-synchronous scans, base-2 domain, unroll-2 ping-pong panels
// (true prefetch distance 2, no register rotation, no barriers).
// ---------------------------------------------------------------------------
#define FWD_LOAD(P, tt) do {                                                   \
    const float* _b = phiN + (size_t)((tt) * NB + n) * 1024;                   \
    _Pragma("unroll")                                                          \
    for (int m = 0; m < 16; ++m) P[m] = _b[(half * 16 + m) * 32 + jl];         \
} while (0)

#define BWD_LOAD(P, tt) do {                                                   \
    const float4* _nb = (const float4*)(phiN + (size_t)((tt) * NB + n) * 1024  \
                                        + (size_t)jl * 32 + half * 16);        \
    float4 _a = _nb[0], _b4 = _nb[1], _c4 = _nb[2], _d4 = _nb[3];              \
    P[0]=_a.x;  P[1]=_a.y;  P[2]=_a.z;  P[3]=_a.w;                             \
    P[4]=_b4.x; P[5]=_b4.y; P[6]=_b4.z; P[7]=_b4.w;                            \
    P[8]=_c4.x; P[9]=_c4.y; P[10]=_c4.z; P[11]=_c4.w;                          \
    P[12]=_d4.x; P[13]=_d4.y; P[14]=_d4.z; P[15]=_d4.w;                        \
} while (0)

#define SCAN_CORE(P, OUTARR, tcur, PREFETCH)                                   \
    do {                                                                       \
        float x[16];                                                           \
        _Pragma("unroll")                                                      \
        for (int m = 0; m < 16; ++m) x[m] = P[m] + carr[m];                    \
        PREFETCH;                                                              \
        float mx = tree_max16(x);                                              \
        float s = tree_sum_exp2_16(x, mx);                                     \
        float mo = __shfl_xor(mx, 32);                                         \
        float so = __shfl_xor(s, 32);                                          \
        float M = fmaxf(mx, mo);                                               \
        s = s * fexp2(mx - M) + so * fexp2(mo - M);                            \
        float nv = M + flog2(s);                                               \
        if (lane < 32) OUTARR[((size_t)(tcur) * NB + n) * SPW + jl] = cj;      \
        cj = nv;                                                               \
        _Pragma("unroll")                                                      \
        for (int m = 0; m < 16; ++m) carr[m] = __shfl(nv, half * 16 + m);      \
    } while (0)

__global__ __launch_bounds__(64) void scan_kernel(
    const float* __restrict__ phiN, float* __restrict__ alphas_pre,
    float* __restrict__ betas_next, float* __restrict__ logZ, float* __restrict__ out)
{
    bool bwd = blockIdx.x >= NB;
    int n = blockIdx.x & (NB - 1);
    int lane = threadIdx.x;
    int half = lane >> 5;
    int jl = lane & 31;
    float carr[16];
#pragma unroll
    for (int m = 0; m < 16; ++m) carr[m] = 0.f;
    float cj = 0.f;
    float pA[16], pB[16];

    if (!bwd) {
        FWD_LOAD(pA, 0);
        FWD_LOAD(pB, 1);
        for (int it = 0; it < TT - 2; it += 2) {
            SCAN_CORE(pA, alphas_pre, it,
                      if (it + 2 < TT - 1) FWD_LOAD(pA, it + 2));
            SCAN_CORE(pB, alphas_pre, it + 1,
                      if (it + 3 < TT - 1) FWD_LOAD(pB, it + 3));
        }
        SCAN_CORE(pA, alphas_pre, TT - 2, );
        // logZ + log_softmax(alpha_T); convert to natural at the boundary
        float mx = cj;
#pragma unroll
        for (int off = 16; off; off >>= 1) mx = fmaxf(mx, __shfl_xor(mx, off));
        float s = fexp2(cj - mx);
#pragma unroll
        for (int off = 16; off; off >>= 1) s += __shfl_xor(s, off);
        float lg = flog2(s);
        if (lane == 0) {
            logZ[n] = (mx + lg) * LN2;       // natural
            logZ[32 + n] = mx + lg;          // base-2 (for elbo)
        }
        if (lane < 32) out[2 + n * 32 + jl] = (cj - mx - lg) * LN2;
    } else {
        BWD_LOAD(pA, TT - 2);
        BWD_LOAD(pB, TT - 3);
        for (int it = TT - 2; it >= 2; it -= 2) {
            SCAN_CORE(pA, betas_next, it,
                      if (it - 2 >= 0) BWD_LOAD(pA, it - 2));
            SCAN_CORE(pB, betas_next, it - 1,
                      if (it - 3 >= 0) BWD_LOAD(pB, it - 3));
        }
        SCAN_CORE(pA, betas_next, 0, );
    }
}

// ---------------------------------------------------------------------------
// K13: elbo — per-block double partial to a PRIVATE slot (NO atomics; the
// single-address done-counter fusion in R12 serialized 4064 blocks — reverted).
// ---------------------------------------------------------------------------
__global__ __launch_bounds__(256) void elbo_kernel(
    const float* __restrict__ phiN, const float* __restrict__ alphas_pre,
    const float* __restrict__ betas_next, const float* __restrict__ logZ,
    double* __restrict__ epart)
{
    int t = blockIdx.x / NB;
    int n = blockIdx.x - t * NB;
    int tid = threadIdx.x;
    __shared__ float ap[32], bn[32];
    if (tid < 32) ap[tid] = alphas_pre[((size_t)t * NB + n) * SPW + tid];
    else if (tid < 64) bn[tid - 32] = betas_next[((size_t)t * NB + n) * SPW + (tid - 32)];
    __syncthreads();
    float lz2 = logZ[32 + n];
    size_t base = (size_t)(t * NB + n) * 1024;
    double local = 0.0;
#pragma unroll
    for (int e = tid; e < 1024; e += 256) {
        int i = e >> 5, j = e & 31;
        float ph2 = phiN[base + e];
        float lm2 = ap[i] + ph2 + bn[j] - lz2;
        local += (double)(fexp2(lm2) * (ph2 * LN2));
    }
#pragma unroll
    for (int off = 32; off; off >>= 1) local += __shfl_down(local, off);
    __shared__ double wsum[4];
    if ((tid & 63) == 0) wsum[tid >> 6] = local;
    __syncthreads();
    if (tid == 0) epart[blockIdx.x] = wsum[0] + wsum[1] + wsum[2] + wsum[3];
}

// ---------------------------------------------------------------------------
// K14: final — sum NTOK partials + logZ sum (kernel boundary = coherence).
// ---------------------------------------------------------------------------
__global__ __launch_bounds__(256) void final_kernel(
    const double* __restrict__ epart, const float* __restrict__ logZ,
    float* __restrict__ out)
{
    int tid = threadIdx.x;
    double local = 0.0;
    for (int i = tid; i < NTOK; i += 256) local += epart[i];
#pragma unroll
    for (int off = 32; off; off >>= 1) local += __shfl_down(local, off);
    __shared__ double wsum[4];
    if ((tid & 63) == 0) wsum[tid >> 6] = local;
    __syncthreads();
    if (tid == 0) {
        out[0] = (float)(wsum[0] + wsum[1] + wsum[2] + wsum[3]);
        float s = 0.f;
        for (int k = 0; k < NB; ++k) s += logZ[k];
        out[1] = s;
    }
}

// ---------------------------------------------------------------------------
extern "C" void kernel_launch(void* const* d_in, const int* in_sizes, int n_in,
                              void* d_out, int out_size, void* d_ws, size_t ws_size,
                              hipStream_t stream) {
    (void)in_sizes; (void)n_in; (void)out_size; (void)ws_size;
    const float* start_emb = (const float*)d_in[0];
    const float* sw1  = (const float*)d_in[1];
    const float* sb1  = (const float*)d_in[2];
    const float* sw2  = (const float*)d_in[3];
    const float* sb2  = (const float*)d_in[4];
    const float* sow  = (const float*)d_in[5];
    const float* state_emb = (const float*)d_in[7];
    const float* tw1  = (const float*)d_in[8];
    const float* tb1  = (const float*)d_in[9];
    const float* tw2  = (const float*)d_in[10];
    const float* tb2  = (const float*)d_in[11];
    const float* nsp  = (const float*)d_in[12];
    const float* pre_emb = (const float*)d_in[13];
    const float* ew1  = (const float*)d_in[14];
    const float* eb1  = (const float*)d_in[15];
    const float* ew2  = (const float*)d_in[16];
    const float* eb2  = (const float*)d_in[17];
    const float* eow  = (const float*)d_in[18];
    const float* eob  = (const float*)d_in[19];
    const int*   text = (const int*)d_in[20];
    const int*   w2s  = (const int*)d_in[21];

    float* ws = (float*)d_ws;
    float* TL      = ws + OFF_TL;
    float* s_tmp   = ws + OFF_STMP;
    float* startl  = ws + OFF_START;
    float* lse1    = ws + OFF_LSE1;
    unsigned* rmax = (unsigned*)(ws + OFF_RMAX);
    float* rsum    = ws + OFF_RSUM;
    float* den     = ws + OFF_DEN;
    float* logZ    = ws + OFF_LOGZ;
    float2* part   = (float2*)(ws + OFF_PART);
    double* epart  = (double*)(ws + OFF_EPART);
    unsigned short* Xp  = (unsigned short*)(ws + OFF_XP);
    unsigned short* Hp  = (unsigned short*)(ws + OFF_HP);
    unsigned short* W1p = (unsigned short*)(ws + OFF_W1P);
    unsigned short* W2p = (unsigned short*)(ws + OFF_W2P);
    unsigned short* Ap  = (unsigned short*)(ws + OFF_AP);
    unsigned short* Bp  = (unsigned short*)(ws + OFF_BP);
    float* ewT     = ws + OFF_EWT;
    float* Lm      = ws + OFF_L;
    float* phiN    = ws + OFF_PHI;
    float* res_e   = ws + OFF_RES_E;
    float* alph    = ws + OFF_ALPH;
    float* beta    = ws + OFF_BETA;
    int* cnt       = (int*)(ws + OFF_CNT);
    int* offs      = (int*)(ws + OFF_OFFS);
    int* cur       = (int*)(ws + OFF_CUR);
    int* ent       = (int*)(ws + OFF_ENT);
    float* out     = (float*)d_out;

    // pack inputs/weights (+ fused accumulator init); MLPs on MFMA
    pack_all_kernel<<<4496, 256, 0, stream>>>(start_emb, state_emb, pre_emb, nsp,
                                              sw1, tw1, ew1, sw2, tw2, ew2,
                                              Xp, Bp, W1p, W2p,
                                              rmax, rsum, cnt, s_tmp);
    gemm_layer1<<<dim3(2, 96), 256, 0, stream>>>(Xp, W1p, sb1, tb1, eb1, Hp);
    gemm_layer2<<<dim3(2, 96), 256, 0, stream>>>(Hp, W2p, sb2, tb2, eb2,
                                                 start_emb, state_emb, pre_emb,
                                                 sow, s_tmp, Ap, res_e);

    // transition path: TL GEMM with contention-free lse partials
    gemm_bt_kernel<<<dim3(32, 32), 256, 0, stream>>>(Ap, Bp, TL, part);

    // emission path (Ap/Bp dead now; ewT overwrites them)
    transpose_kernel<<<dim3(V_ / 32, H_ / 32), 256, 0, stream>>>(eow, ewT);
    em_logits_kernel<<<V_, 256, 0, stream>>>(res_e, ewT, eob, w2s, Lm, rmax);
    row_sum_kernel<<<V_ / 8, 256, 0, stream>>>(w2s, Lm, rmax, rsum);
    denom_hist_lse_kernel<<<16 + NITEM / 256 + 1024 + 1, 256, 0, stream>>>(
        rmax, rsum, den, text, w2s, cnt, part, lse1, s_tmp, startl);
    prefix_kernel<<<1, 1024, 0, stream>>>(cnt, offs, cur);
    fill_kernel<<<NITEM / 256, 256, 0, stream>>>(text, w2s, cur, ent);

    // phi assembly (obs inline, base-2 scaled) + scans + outputs
    phi_gather_kernel<<<C_, 256, 0, stream>>>(TL, offs, ent, lse1, startl,
                                              Lm, den, text, w2s, phiN);
    scan_kernel<<<2 * NB, 64, 0, stream>>>(phiN, alph, beta, logZ, out);
    elbo_kernel<<<NTOK, 256, 0, stream>>>(phiN, alph, beta, logZ, epart);
    final_kernel<<<1, 256, 0, stream>>>(epart, logZ, out);
}

// Round 14
// 436.422 us; speedup vs baseline: 1.1882x; 1.0216x over previous
//
#include <hip/hip_runtime.h>
#include <hip/hip_fp16.h>
#include <math.h>

// Problem constants (fixed by the reference)
#define C_   4096
#define H_   256
#define V_   16000
#define SPW  32
#define NB   32    // N (batch)
#define TT   128   // T (sequence length)
#define NTOK ((TT - 1) * NB)          // 4064 token transitions
#define NITEM (NTOK * SPW)            // 130048 (nt, i) row-uses
#define GEMM_K 768                    // 3 x 256 split-fp16 segments (layer GEMMs)
#define BT_K  512                     // [hi|lo] packing for the TL GEMM
#define LOG2E 1.44269504088896340736f
#define LN2   0.69314718055994530942f

// raw hardware transcendentals (v_exp_f32 computes 2^x, v_log_f32 is log2).
__device__ inline float fexp2(float x) { return __builtin_amdgcn_exp2f(x); }
__device__ inline float flog2(float x) { return __builtin_amdgcn_logf(x); }

// ---------------------------------------------------------------------------
// Workspace layout (float offsets). Total ~27.0M floats = ~108 MB.
// ---------------------------------------------------------------------------
static const size_t OFF_TL    = 0;                                   // C*C transition logits
static const size_t OFF_RES   = OFF_TL   + (size_t)C_ * C_;          // C*H spare: lse partials (4 MB exact)
static const size_t OFF_STMP  = OFF_RES  + (size_t)C_ * H_;          // C   start pre-softmax
static const size_t OFF_START = OFF_STMP + C_;                       // C   start log-probs
static const size_t OFF_LSE1  = OFF_START + C_;                      // C
static const size_t OFF_LSE2  = OFF_LSE1 + C_;                       // C (spare)
static const size_t OFF_RMAX  = OFF_LSE2 + C_;                       // C (unsigned, encoded-float max)
static const size_t OFF_RSUM  = OFF_RMAX + C_;                       // C
static const size_t OFF_DEN   = OFF_RSUM + C_;                       // C emission row log-denominator
static const size_t OFF_LOGZ  = OFF_DEN  + C_;                       // [0,32) natural; [32,64) base-2
static const size_t OFF_ELBO  = OFF_LOGZ + 64;                       // (spare)
static const size_t OFF_EWT   = OFF_ELBO + 16;                       // V*H region (Ap/Bp early, ewT later)
static const size_t OFF_L     = OFF_EWT  + (size_t)V_ * H_;          // V*SPW masked emission logits
static const size_t OFF_OBS   = OFF_L    + (size_t)V_ * SPW;         // elbo partials (obs deleted)
static const size_t OFF_PHI   = OFF_OBS  + (size_t)NB * TT * SPW;    // phiN[t,n,i,j] * LOG2E (base-2)
static const size_t OFF_ALPH  = OFF_PHI  + (size_t)NTOK * SPW * SPW; // (T-1)*N*SPW (base-2)
static const size_t OFF_BETA  = OFF_ALPH + (size_t)NTOK * SPW;       // (T-1)*N*SPW (base-2)

// lse partials: part[row][slice], 4096 x 128 float2 = 1,048,576 floats (exact RES fit)
static const size_t OFF_PART  = OFF_RES;
// elbo per-block partials: NTOK doubles in the freed obs region (8B aligned)
static const size_t OFF_EPART = OFF_OBS;

// MLP GEMM scratch aliased onto TL region (dead until gemm_bt writes TL):
static const size_t OFF_XP    = OFF_TL;                                   // 12288x768 us
static const size_t OFF_HP    = OFF_TL + (size_t)3 * C_ * GEMM_K / 2;     // 12288x768 us
static const size_t OFF_W1P   = OFF_TL + (size_t)6 * C_ * GEMM_K / 2;     // 3 x 256x768 us
static const size_t OFF_W2P   = OFF_W1P + (size_t)3 * 256 * GEMM_K / 2;

// Ap/Bp (TL-GEMM operands, K=512 [hi|lo]) in the ewT region; ewT overwrites
// them after gemm_bt has consumed Ap/Bp.
static const size_t OFF_AP    = OFF_EWT;                              // 4096x512 us
static const size_t OFF_BP    = OFF_EWT + (size_t)C_ * BT_K / 2;      // 4096x512 us

// res_e aliased onto phi region (phi written much later by phi_gather).
static const size_t OFF_RES_E = OFF_PHI + (size_t)C_ * H_;

// Inverted-index scratch aliased onto alpha/beta region (dead until scan).
static const size_t OFF_CNT   = OFF_ALPH;            // 4096 int
static const size_t OFF_OFFS  = OFF_ALPH + 4096;     // 4097 int (pad to 4112)
static const size_t OFF_CUR   = OFF_ALPH + 8208;     // 4096 int
static const size_t OFF_ENT   = OFF_ALPH + 12304;    // NITEM int

// Monotone float<->uint encoding for atomicMax on floats (handles negatives)
__device__ inline unsigned enc_f(float f) {
    unsigned u = __float_as_uint(f);
    return (u & 0x80000000u) ? ~u : (u | 0x80000000u);
}
__device__ inline float dec_f(unsigned k) {
    return (k & 0x80000000u) ? __uint_as_float(k ^ 0x80000000u) : __uint_as_float(~k);
}

__device__ inline void split_h(float v, unsigned short& hi, unsigned short& lo) {
    __half h = __float2half(v);
    __half l = __float2half(v - __half2float(h));
    __builtin_memcpy(&hi, &h, 2);
    __builtin_memcpy(&lo, &l, 2);
}

typedef __attribute__((ext_vector_type(8))) short short8;
typedef __attribute__((ext_vector_type(4))) float floatx4;

#define GLB(p)  ((const __attribute__((address_space(1))) unsigned int*)(p))
#define LDSP(p) ((__attribute__((address_space(3))) unsigned int*)(p))

// ---------------------------------------------------------------------------
// K1: pack everything to split-fp16; trailing 16 blocks do accumulator init.
// Xp/W1p/W2p keep the K=768 layer layout; Bp is K=512 [hi|lo] for gemm_bt.
// ---------------------------------------------------------------------------
__global__ __launch_bounds__(256) void pack_all_kernel(
    const float* __restrict__ se, const float* __restrict__ ste, const float* __restrict__ pe,
    const float* __restrict__ nsp,
    const float* __restrict__ w1_0, const float* __restrict__ w1_1, const float* __restrict__ w1_2,
    const float* __restrict__ w2_0, const float* __restrict__ w2_1, const float* __restrict__ w2_2,
    unsigned short* __restrict__ Xp, unsigned short* __restrict__ Bp,
    unsigned short* __restrict__ W1p, unsigned short* __restrict__ W2p,
    unsigned* __restrict__ rowmax, float* __restrict__ rowsum,
    int* __restrict__ cnt, float* __restrict__ s_tmp)
{
    __shared__ float tile_s[32][33];
    int blk = blockIdx.x;
    if (blk < 4096) {
        bool isB = blk >= 3072;
        int e4 = (isB ? blk - 3072 : blk) * 256 + threadIdx.x;
        int r = e4 >> 6;
        int c = (e4 & 63) * 4;
        const float* src;
        unsigned short* dst;
        if (isB) { src = nsp + (size_t)r * H_; dst = Bp; }
        else {
            int inst = r >> 12;
            int rl = r & 4095;
            src = (inst == 0 ? se : inst == 1 ? ste : pe) + (size_t)rl * H_;
            dst = Xp;
        }
        float4 v = *(const float4*)(src + c);
        float vv[4] = {v.x, v.y, v.z, v.w};
        union { unsigned short s[4]; ushort4 u; } hi, lo;
#pragma unroll
        for (int q = 0; q < 4; ++q) split_h(vv[q], hi.s[q], lo.s[q]);
        if (!isB) {   // A-layout [hi | lo | hi], K=768 (layer GEMMs)
            size_t base = (size_t)r * GEMM_K + c;
            *(ushort4*)&dst[base]       = hi.u;
            *(ushort4*)&dst[base + 256] = lo.u;
            *(ushort4*)&dst[base + 512] = hi.u;
        } else {      // B-layout [hi | lo], K=512 (TL GEMM)
            size_t base = (size_t)r * BT_K + c;
            *(ushort4*)&dst[base]       = hi.u;
            *(ushort4*)&dst[base + 256] = lo.u;
        }
    } else if (blk < 4480) {
        int b = blk - 4096;
        int mat = b >> 6, tile = b & 63;
        int n0 = (tile & 7) * 32, k0 = (tile >> 3) * 32;
        const float* W = mat == 0 ? w1_0 : mat == 1 ? w1_1 : mat == 2 ? w1_2
                       : mat == 3 ? w2_0 : mat == 4 ? w2_1 : w2_2;
        unsigned short* dst = (mat < 3) ? W1p + (size_t)mat * 256 * GEMM_K
                                        : W2p + (size_t)(mat - 3) * 256 * GEMM_K;
        int tx = threadIdx.x & 31, ty = threadIdx.x >> 5;
#pragma unroll
        for (int q = 0; q < 4; ++q)
            tile_s[ty + 8 * q][tx] = W[(size_t)(k0 + ty + 8 * q) * 256 + n0 + tx];
        __syncthreads();
#pragma unroll
        for (int q = 0; q < 4; ++q) {
            float v = tile_s[tx][ty + 8 * q];
            unsigned short hi, lo;
            split_h(v, hi, lo);
            size_t ob = (size_t)(n0 + ty + 8 * q) * GEMM_K + k0 + tx;
            dst[ob] = hi; dst[ob + 256] = hi; dst[ob + 512] = lo;
        }
    } else {
        int i = (blk - 4480) * 256 + threadIdx.x;   // < 4096
        rowmax[i] = 0u; rowsum[i] = 0.f; cnt[i] = 0; s_tmp[i] = 0.f;
    }
}

// ---------------------------------------------------------------------------
// Shared layer-GEMM core: 128x128 tile, 4 waves of 64x64, K=768.
// ---------------------------------------------------------------------------
#define GEMM_PROLOGUE(APTR, BPTR)                                              \
    __shared__ __align__(16) unsigned short As[128 * 64];                      \
    __shared__ __align__(16) unsigned short Bs[128 * 64];                      \
    int tid = threadIdx.x;                                                     \
    int wave = tid >> 6, lane = tid & 63;                                      \
    int wm = (wave & 1) * 64, wn = (wave >> 1) * 64;                           \
    int l15 = lane & 15, quad = lane >> 4;                                     \
    floatx4 acc[4][4] = {};                                                    \
    int c0row = tid >> 3;                                                      \
    int c0col = (tid & 7) * 8;                                                 \
    for (int k0 = 0; k0 < GEMM_K; k0 += 64) {                                  \
        __syncthreads();                                                       \
        _Pragma("unroll")                                                      \
        for (int q = 0; q < 4; ++q) {                                          \
            int row = c0row + q * 32;                                          \
            const unsigned short* ga = (APTR) + (size_t)(i0 + row) * GEMM_K + k0 + c0col; \
            const unsigned short* gb = (BPTR) + (size_t)(j0 + row) * GEMM_K + k0 + c0col; \
            __builtin_amdgcn_global_load_lds(GLB(ga), LDSP(&As[(size_t)row * 64 + c0col]), 16, 0, 0); \
            __builtin_amdgcn_global_load_lds(GLB(gb), LDSP(&Bs[(size_t)row * 64 + c0col]), 16, 0, 0); \
        }                                                                      \
        __syncthreads();                                                       \
        _Pragma("unroll")                                                      \
        for (int ks = 0; ks < 64; ks += 32) {                                  \
            short8 af[4], bfr[4];                                              \
            _Pragma("unroll")                                                  \
            for (int mi = 0; mi < 4; ++mi)                                     \
                af[mi] = *(const short8*)&As[(wm + mi * 16 + l15) * 64 + ks + quad * 8]; \
            _Pragma("unroll")                                                  \
            for (int ni = 0; ni < 4; ++ni)                                     \
                bfr[ni] = *(const short8*)&Bs[(wn + ni * 16 + l15) * 64 + ks + quad * 8]; \
            _Pragma("unroll")                                                  \
            for (int mi = 0; mi < 4; ++mi)                                     \
                _Pragma("unroll")                                              \
                for (int ni = 0; ni < 4; ++ni)                                 \
                    acc[mi][ni] = __builtin_amdgcn_mfma_f32_16x16x32_f16(      \
                        af[mi], bfr[ni], acc[mi][ni], 0, 0, 0);                \
        }                                                                      \
    }

// ---------------------------------------------------------------------------
// K2: MLP layer 1: H = relu(X@W1 + b1), packed split-fp16 out (A-layout 768).
// ---------------------------------------------------------------------------
__global__ __launch_bounds__(256) void gemm_layer1(
    const unsigned short* __restrict__ Xp, const unsigned short* __restrict__ Wp,
    const float* __restrict__ b0, const float* __restrict__ b1, const float* __restrict__ b2,
    unsigned short* __restrict__ Hp)
{
    int i0 = blockIdx.y * 128, j0 = blockIdx.x * 128;
    int inst = blockIdx.y >> 5;
    const unsigned short* Wbase = Wp + (size_t)inst * 256 * GEMM_K;
    const float* bias = inst == 0 ? b0 : (inst == 1 ? b1 : b2);
    GEMM_PROLOGUE(Xp, Wbase)
#pragma unroll
    for (int mi = 0; mi < 4; ++mi) {
#pragma unroll
        for (int reg = 0; reg < 4; ++reg) {
            int row = i0 + wm + mi * 16 + quad * 4 + reg;
#pragma unroll
            for (int ni = 0; ni < 4; ++ni) {
                int col = j0 + wn + ni * 16 + l15;
                float h = fmaxf(acc[mi][ni][reg] + bias[col], 0.f);
                unsigned short hi, lo;
                split_h(h, hi, lo);
                size_t base = (size_t)row * GEMM_K + col;
                Hp[base] = hi; Hp[base + 256] = lo; Hp[base + 512] = hi;
            }
        }
    }
}

// ---------------------------------------------------------------------------
// K3: MLP layer 2: Z = relu(H@W2 + b2) + X, per-instance epilogue.
// inst 1 now packs Ap as K=512 [hi|lo] for the restructured TL GEMM.
// ---------------------------------------------------------------------------
__global__ __launch_bounds__(256) void gemm_layer2(
    const unsigned short* __restrict__ Hp, const unsigned short* __restrict__ Wp,
    const float* __restrict__ b0, const float* __restrict__ b1, const float* __restrict__ b2,
    const float* __restrict__ x0, const float* __restrict__ x1, const float* __restrict__ x2,
    const float* __restrict__ sow, float* __restrict__ s_tmp,
    unsigned short* __restrict__ Ap, float* __restrict__ res_e)
{
    int i0 = blockIdx.y * 128, j0 = blockIdx.x * 128;
    int inst = blockIdx.y >> 5;
    const unsigned short* Wbase = Wp + (size_t)inst * 256 * GEMM_K;
    const float* bias = inst == 0 ? b0 : (inst == 1 ? b1 : b2);
    const float* X = inst == 0 ? x0 : (inst == 1 ? x1 : x2);
    GEMM_PROLOGUE(Hp, Wbase)
#pragma unroll
    for (int mi = 0; mi < 4; ++mi) {
#pragma unroll
        for (int reg = 0; reg < 4; ++reg) {
            int row = i0 + wm + mi * 16 + quad * 4 + reg;
            int rl = row & 4095;
            float ps = 0.f;
#pragma unroll
            for (int ni = 0; ni < 4; ++ni) {
                int col = j0 + wn + ni * 16 + l15;
                float z = fmaxf(acc[mi][ni][reg] + bias[col], 0.f)
                        + X[(size_t)rl * H_ + col];
                if (inst == 0) {
                    ps += z * sow[col];
                } else if (inst == 1) {
                    unsigned short hi, lo;
                    split_h(z, hi, lo);
                    size_t base = (size_t)rl * BT_K + col;
                    Ap[base] = hi; Ap[base + 256] = lo;
                } else {
                    res_e[(size_t)rl * H_ + col] = z;
                }
            }
            if (inst == 0) {
                ps += __shfl_xor(ps, 1);
                ps += __shfl_xor(ps, 2);
                ps += __shfl_xor(ps, 4);
                ps += __shfl_xor(ps, 8);
                if (l15 == 0) atomicAdd(&s_tmp[rl], ps);
            }
        }
    }
}

// ---------------------------------------------------------------------------
// K4: TL = Ahi.Bhi^T + Alo.Bhi^T + Ahi.Blo^T  (K=512 [hi|lo] operands).
// Stages 4 tiles (64 KB LDS) per 64-chunk; A1/B1 fragments reused across the
// 3 MFMA products -> ds_read traffic -33%, barriers 24->8 vs the K=768 form.
// Identical arithmetic (same 3 products into one accumulator).
// ---------------------------------------------------------------------------
__global__ __launch_bounds__(256) void gemm_bt_kernel(
    const unsigned short* __restrict__ Ap, const unsigned short* __restrict__ Bp,
    float* __restrict__ Cmat, float2* __restrict__ part)
{
    __shared__ __align__(16) unsigned short A1s[128 * 64];
    __shared__ __align__(16) unsigned short A2s[128 * 64];
    __shared__ __align__(16) unsigned short B1s[128 * 64];
    __shared__ __align__(16) unsigned short B2s[128 * 64];
    int tid = threadIdx.x;
    int wave = tid >> 6, lane = tid & 63;
    int wm = (wave & 1) * 64, wn = (wave >> 1) * 64;
    int l15 = lane & 15, quad = lane >> 4;
    floatx4 acc[4][4] = {};
    int c0row = tid >> 3;          // 0..31
    int c0col = (tid & 7) * 8;     // 0,8,..,56
    int i0 = blockIdx.y * 128, j0 = blockIdx.x * 128;

    for (int kc = 0; kc < 256; kc += 64) {
        __syncthreads();
#pragma unroll
        for (int q = 0; q < 4; ++q) {
            int row = c0row + q * 32;
            const unsigned short* gA = Ap + (size_t)(i0 + row) * BT_K + kc + c0col;
            const unsigned short* gB = Bp + (size_t)(j0 + row) * BT_K + kc + c0col;
            __builtin_amdgcn_global_load_lds(GLB(gA),       LDSP(&A1s[(size_t)row * 64 + c0col]), 16, 0, 0);
            __builtin_amdgcn_global_load_lds(GLB(gA + 256), LDSP(&A2s[(size_t)row * 64 + c0col]), 16, 0, 0);
            __builtin_amdgcn_global_load_lds(GLB(gB),       LDSP(&B1s[(size_t)row * 64 + c0col]), 16, 0, 0);
            __builtin_amdgcn_global_load_lds(GLB(gB + 256), LDSP(&B2s[(size_t)row * 64 + c0col]), 16, 0, 0);
        }
        __syncthreads();
#pragma unroll
        for (int ks = 0; ks < 64; ks += 32) {
            short8 a1[4], a2[4], b1[4], b2[4];
#pragma unroll
            for (int mi = 0; mi < 4; ++mi) {
                a1[mi] = *(const short8*)&A1s[(wm + mi * 16 + l15) * 64 + ks + quad * 8];
                a2[mi] = *(const short8*)&A2s[(wm + mi * 16 + l15) * 64 + ks + quad * 8];
            }
#pragma unroll
            for (int ni = 0; ni < 4; ++ni) {
                b1[ni] = *(const short8*)&B1s[(wn + ni * 16 + l15) * 64 + ks + quad * 8];
                b2[ni] = *(const short8*)&B2s[(wn + ni * 16 + l15) * 64 + ks + quad * 8];
            }
#pragma unroll
            for (int mi = 0; mi < 4; ++mi)
#pragma unroll
                for (int ni = 0; ni < 4; ++ni) {
                    acc[mi][ni] = __builtin_amdgcn_mfma_f32_16x16x32_f16(a1[mi], b1[ni], acc[mi][ni], 0, 0, 0);
                    acc[mi][ni] = __builtin_amdgcn_mfma_f32_16x16x32_f16(a2[mi], b1[ni], acc[mi][ni], 0, 0, 0);
                    acc[mi][ni] = __builtin_amdgcn_mfma_f32_16x16x32_f16(a1[mi], b2[ni], acc[mi][ni], 0, 0, 0);
                }
        }
    }
    // epilogue: C store + per-row lse partials (3 shuffle levels, 128 slices)
    int slice = (blockIdx.x * 2 + (wave >> 1)) * 2;
#pragma unroll
    for (int mi = 0; mi < 4; ++mi) {
#pragma unroll
        for (int reg = 0; reg < 4; ++reg) {
            int row = i0 + wm + mi * 16 + quad * 4 + reg;
            float* crow = Cmat + (size_t)row * C_ + j0 + wn;
#pragma unroll
            for (int ni = 0; ni < 4; ++ni)
                crow[ni * 16 + l15] = acc[mi][ni][reg];
            float m = fmaxf(fmaxf(acc[mi][0][reg], acc[mi][1][reg]),
                            fmaxf(acc[mi][2][reg], acc[mi][3][reg]));
            float s = __expf(acc[mi][0][reg] - m) + __expf(acc[mi][1][reg] - m)
                    + __expf(acc[mi][2][reg] - m) + __expf(acc[mi][3][reg] - m);
#pragma unroll
            for (int off = 1; off <= 4; off <<= 1) {
                float mo = __shfl_xor(m, off);
                float so = __shfl_xor(s, off);
                float M = fmaxf(m, mo);
                s = s * __expf(m - M) + so * __expf(mo - M);
                m = M;
            }
            if ((l15 & 7) == 0)
                part[(size_t)row * 128 + slice + (l15 >> 3)] = make_float2(m, s);
        }
    }
}

// ---------------------------------------------------------------------------
// K5: transpose e_out_w (H,V) -> ewT (V,H)  (overwrites dead Ap/Bp region)
// ---------------------------------------------------------------------------
__global__ __launch_bounds__(256) void transpose_kernel(
    const float* __restrict__ W, float* __restrict__ WT)
{
    __shared__ float tile[32][33];
    int tx = threadIdx.x & 31, ty = threadIdx.x >> 5;
    int v0 = blockIdx.x * 32, h0 = blockIdx.y * 32;
#pragma unroll
    for (int q = 0; q < 4; ++q)
        tile[ty + 8 * q][tx] = W[(size_t)(h0 + ty + 8 * q) * V_ + v0 + tx];
    __syncthreads();
#pragma unroll
    for (int q = 0; q < 4; ++q)
        WT[(size_t)(v0 + ty + 8 * q) * H_ + h0 + tx] = tile[tx][ty + 8 * q];
}

// ---------------------------------------------------------------------------
// K6: masked emission logits + FUSED per-state rowmax scatter (deduped).
// ---------------------------------------------------------------------------
__global__ __launch_bounds__(256) void em_logits_kernel(
    const float* __restrict__ res_pre, const float* __restrict__ ewT,
    const float* __restrict__ eob, const int* __restrict__ w2s,
    float* __restrict__ L, unsigned* __restrict__ rowmax)
{
    int v = blockIdx.x;
    __shared__ __align__(16) float wv[H_];
    __shared__ int st[32];
    wv[threadIdx.x] = ewT[(size_t)v * H_ + threadIdx.x];
    int g = threadIdx.x >> 3;
    int l = threadIdx.x & 7;
    int c = w2s[v * SPW + g];
    if (l == 0) st[g] = c;
    __syncthreads();
    const float4* row4 = (const float4*)(res_pre + (size_t)c * H_);
    const float4* wv4 = (const float4*)wv;
    float sum = 0.f;
#pragma unroll
    for (int m = 0; m < 8; ++m) {
        float4 r = row4[l + m * 8];
        float4 w = wv4[l + m * 8];
        sum += r.x * w.x + r.y * w.y + r.z * w.z + r.w * w.w;
    }
    sum += __shfl_xor(sum, 1);
    sum += __shfl_xor(sum, 2);
    sum += __shfl_xor(sum, 4);
    if (l == 0) {
        float logit = sum + eob[v];
        L[v * SPW + g] = logit;
        bool dup = false;
        for (int kp = 0; kp < g; ++kp) if (st[kp] == c) { dup = true; break; }
        if (!dup) atomicMax(&rowmax[c], enc_f(logit));
    }
}

// ---------------------------------------------------------------------------
// K7: scatter per-state sum(exp(x-max)), deduping repeated states
// ---------------------------------------------------------------------------
__global__ __launch_bounds__(256) void row_sum_kernel(
    const int* __restrict__ w2s, const float* __restrict__ L,
    const unsigned* __restrict__ rowmax, float* __restrict__ rowsum)
{
    __shared__ int st[8][32];
    int vl = threadIdx.x >> 5, k = threadIdx.x & 31;
    int v = blockIdx.x * 8 + vl;
    st[vl][k] = w2s[v * SPW + k];
    __syncthreads();
    int c = st[vl][k];
    bool dup = false;
    for (int kp = 0; kp < k; ++kp) if (st[vl][kp] == c) { dup = true; break; }
    if (!dup) atomicAdd(&rowsum[c], expf(L[v * SPW + k] - dec_f(rowmax[c])));
}

// ---------------------------------------------------------------------------
// K8: fused: denom (blocks 0..15) + hist (16..523) + lse1 fold (one wave per
// row, 128 partials each: 524..1547) + start log_softmax (block 1548).
// ---------------------------------------------------------------------------
__global__ __launch_bounds__(256) void denom_hist_lse_kernel(
    const unsigned* __restrict__ rowmax, const float* __restrict__ rowsum,
    float* __restrict__ denom, const int* __restrict__ text,
    const int* __restrict__ w2s, int* __restrict__ count,
    const float2* __restrict__ part, float* __restrict__ lse1,
    const float* __restrict__ s_tmp, float* __restrict__ startl)
{
    int blk = blockIdx.x;
    if (blk < 16) {
        int c = blk * 256 + threadIdx.x;
        unsigned k = rowmax[c];
        denom[c] = (k == 0u) ? -INFINITY : (dec_f(k) + logf(rowsum[c]));
    } else if (blk < 16 + NITEM / 256) {
        int item = (blk - 16) * 256 + threadIdx.x;
        int i  = item & 31;
        int nt = item >> 5;
        int t = nt >> 5, n = nt & 31;
        int v0 = text[n * TT + t];
        int ci = w2s[v0 * SPW + i];
        atomicAdd(&count[ci], 1);
    } else if (blk < 16 + NITEM / 256 + 1024) {
        int row = (blk - 16 - NITEM / 256) * 4 + (threadIdx.x >> 6);
        int lane = threadIdx.x & 63;
        const float2* pr = part + (size_t)row * 128;
        float2 p0 = pr[lane];
        float2 p1 = pr[64 + lane];
        float m = fmaxf(p0.x, p1.x);
        float s = p0.y * __expf(p0.x - m) + p1.y * __expf(p1.x - m);
#pragma unroll
        for (int off = 1; off <= 32; off <<= 1) {
            float mo = __shfl_xor(m, off);
            float so = __shfl_xor(s, off);
            float M = fmaxf(m, mo);
            s = s * __expf(m - M) + so * __expf(mo - M);
            m = M;
        }
        if (lane == 0) lse1[row] = m + logf(s);
    } else {
        __shared__ float red_m[4];
        __shared__ float red_s[4];
        int t = threadIdx.x;
        float v[16];
        float mx = -INFINITY;
#pragma unroll
        for (int q = 0; q < 16; ++q) { v[q] = s_tmp[t + q * 256]; mx = fmaxf(mx, v[q]); }
#pragma unroll
        for (int off = 32; off; off >>= 1) mx = fmaxf(mx, __shfl_xor(mx, off));
        if ((t & 63) == 0) red_m[t >> 6] = mx;
        __syncthreads();
        float M = fmaxf(fmaxf(red_m[0], red_m[1]), fmaxf(red_m[2], red_m[3]));
        float sm = 0.f;
#pragma unroll
        for (int q = 0; q < 16; ++q) sm += __expf(v[q] - M);
#pragma unroll
        for (int off = 32; off; off >>= 1) sm += __shfl_xor(sm, off);
        if ((t & 63) == 0) red_s[t >> 6] = sm;
        __syncthreads();
        float S = red_s[0] + red_s[1] + red_s[2] + red_s[3];
        float lg = logf(S);
#pragma unroll
        for (int q = 0; q < 16; ++q) startl[t + q * 256] = (v[q] - M) - lg;
    }
}

// ---------------------------------------------------------------------------
// K9: single-block 1024-thread prefix scan of counts.
// ---------------------------------------------------------------------------
__global__ __launch_bounds__(1024) void prefix_kernel(
    const int* __restrict__ count, int* __restrict__ offs, int* __restrict__ cursor)
{
    __shared__ int buf[1024];
    int t = threadIdx.x;
    int c0 = count[t * 4 + 0], c1 = count[t * 4 + 1];
    int c2 = count[t * 4 + 2], c3 = count[t * 4 + 3];
    int s = c0 + c1 + c2 + c3;
    buf[t] = s;
    __syncthreads();
    for (int d = 1; d < 1024; d <<= 1) {
        int v = (t >= d) ? buf[t - d] : 0;
        __syncthreads();
        buf[t] += v;
        __syncthreads();
    }
    int excl = buf[t] - s;
    offs[t * 4 + 0] = excl; cursor[t * 4 + 0] = excl; excl += c0;
    offs[t * 4 + 1] = excl; cursor[t * 4 + 1] = excl; excl += c1;
    offs[t * 4 + 2] = excl; cursor[t * 4 + 2] = excl; excl += c2;
    offs[t * 4 + 3] = excl; cursor[t * 4 + 3] = excl;
    if (t == 1023) offs[4096] = buf[1023];
}

// ---------------------------------------------------------------------------
// K10: index fill (obs computed inline in phi_gather)
// ---------------------------------------------------------------------------
__global__ void fill_kernel(const int* __restrict__ text, const int* __restrict__ w2s,
                            int* __restrict__ cursor, int* __restrict__ entries)
{
    int item = blockIdx.x * 256 + threadIdx.x;
    int i  = item & 31;
    int nt = item >> 5;
    int t = nt >> 5, n = nt & 31;
    int v0 = text[n * TT + t];
    int ci = w2s[v0 * SPW + i];
    int pos = atomicAdd(&cursor[ci], 1);
    entries[pos] = item;
}

// ---------------------------------------------------------------------------
// K11: phi gather, inverted, obs computed inline (Lm/den gathers, L1-served).
// phiN layout: [t, n, i, j] (j innermost), scaled by LOG2E (base-2 domain).
// ---------------------------------------------------------------------------
__global__ __launch_bounds__(256) void phi_gather_kernel(
    const float* __restrict__ TL, const int* __restrict__ offs, const int* __restrict__ entries,
    const float* __restrict__ lse1, const float* __restrict__ start_log,
    const float* __restrict__ Lm, const float* __restrict__ den,
    const int* __restrict__ text, const int* __restrict__ w2s, float* __restrict__ phiN)
{
    int ci = blockIdx.x;
    __shared__ float row[C_];   // 16 KB
    {
        const float4* src = (const float4*)(TL + (size_t)ci * C_);
        float4* dst = (float4*)row;
        for (int q = threadIdx.x; q < C_ / 4; q += 256) dst[q] = src[q];
    }
    __syncthreads();
    float abase = -lse1[ci];
    float st = start_log[ci];
    float dci = den[ci];
    int beg = offs[ci], end = offs[ci + 1];
    int g = threadIdx.x >> 5, lane = threadIdx.x & 31;
    for (int idx = beg + g; idx < end; idx += 8) {
        int item = entries[idx];
        int i  = item & 31;
        int nt = item >> 5;
        int t = nt >> 5, n = nt & 31;
        int v1 = text[n * TT + t + 1];
        int cj = w2s[v1 * SPW + lane];
        float ob = Lm[v1 * SPW + lane] - den[cj];
        float a = abase;
        if (t == 0) {
            int v0 = text[n * TT];
            a += st + (Lm[v0 * SPW + i] - dci);
        }
        phiN[(size_t)nt * 1024 + i * 32 + lane] = (row[cj] + a + ob) * LOG2E;
    }
}

// tree helpers over a 16-register panel (explicit log-depth reductions)
__device__ inline float tree_max16(const float* x) {
    float r0 = fmaxf(x[0], x[8]),  r1 = fmaxf(x[1], x[9]);
    float r2 = fmaxf(x[2], x[10]), r3 = fmaxf(x[3], x[11]);
    float r4 = fmaxf(x[4], x[12]), r5 = fmaxf(x[5], x[13]);
    float r6 = fmaxf(x[6], x[14]), r7 = fmaxf(x[7], x[15]);
    r0 = fmaxf(r0, r4); r1 = fmaxf(r1, r5); r2 = fmaxf(r2, r6); r3 = fmaxf(r3, r7);
    r0 = fmaxf(r0, r2); r1 = fmaxf(r1, r3);
    return fmaxf(r0, r1);
}
__device__ inline float tree_sum_exp2_16(const float* x, float mx) {
    float e0 = fexp2(x[0] - mx),  e1 = fexp2(x[1] - mx);
    float e2 = fexp2(x[2] - mx),  e3 = fexp2(x[3] - mx);
    float e4 = fexp2(x[4] - mx),  e5 = fexp2(x[5] - mx);
    float e6 = fexp2(x[6] - mx),  e7 = fexp2(x[7] - mx);
    float e8 = fexp2(x[8] - mx),  e9 = fexp2(x[9] - mx);
    float ea = fexp2(x[10] - mx), eb = fexp2(x[11] - mx);
    float ec = fexp2(x[12] - mx), ed = fexp2(x[13] - mx);
    float ee = fexp2(x[14] - mx), ef = fexp2(x[15] - mx);
    e0 += e8; e1 += e9; e2 += ea; e3 += eb; e4 += ec; e5 += ed; e6 += ee; e7 += ef;
    e0 += e4; e1 += e5; e2 += e6; e3 += e7;
    e0 += e2; e1 += e3;
    return e0 + e1;
}

// ---------------------------------------------------------------------------
// K12: wave-synchronous scans, base-2 domain, unroll-2 ping-pong panels.
// ---------------------------------------------------------------------------
#define FWD_LOAD(P, tt) do {                                                   \
    const float* _b = phiN + (size_t)((tt) * NB + n) * 1024;                   \
    _Pragma("unroll")                                                          \
    for (int m = 0; m < 16; ++m) P[m] = _b[(half * 16 + m) * 32 + jl];         \
} while (0)

#define BWD_LOAD(P, tt) do {                                                   \
    const float4* _nb = (const float4*)(phiN + (size_t)((tt) * NB + n) * 1024  \
                                        + (size_t)jl * 32 + half * 16);        \
    float4 _a = _nb[0], _b4 = _nb[1], _c4 = _nb[2], _d4 = _nb[3];              \
    P[0]=_a.x;  P[1]=_a.y;  P[2]=_a.z;  P[3]=_a.w;                             \
    P[4]=_b4.x; P[5]=_b4.y; P[6]=_b4.z; P[7]=_b4.w;                            \
    P[8]=_c4.x; P[9]=_c4.y; P[10]=_c4.z; P[11]=_c4.w;                          \
    P[12]=_d4.x; P[13]=_d4.y; P[14]=_d4.z; P[15]=_d4.w;                        \
} while (0)

#define SCAN_CORE(P, OUTARR, tcur, PREFETCH)                                   \
    do {                                                                       \
        float x[16];                                                           \
        _Pragma("unroll")                                                      \
        for (int m = 0; m < 16; ++m) x[m] = P[m] + carr[m];                    \
        PREFETCH;                                                              \
        float mx = tree_max16(x);                                              \
        float s = tree_sum_exp2_16(x, mx);                                     \
        float mo = __shfl_xor(mx, 32);                                         \
        float so = __shfl_xor(s, 32);                                          \
        float M = fmaxf(mx, mo);                                               \
        s = s * fexp2(mx - M) + so * fexp2(mo - M);                            \
        float nv = M + flog2(s);                                               \
        if (lane < 32) OUTARR[((size_t)(tcur) * NB + n) * SPW + jl] = cj;      \
        cj = nv;                                                               \
        _Pragma("unroll")                                                      \
        for (int m = 0; m < 16; ++m) carr[m] = __shfl(nv, half * 16 + m);      \
    } while (0)

__global__ __launch_bounds__(64) void scan_kernel(
    const float* __restrict__ phiN, float* __restrict__ alphas_pre,
    float* __restrict__ betas_next, float* __restrict__ logZ, float* __restrict__ out)
{
    bool bwd = blockIdx.x >= NB;
    int n = blockIdx.x & (NB - 1);
    int lane = threadIdx.x;
    int half = lane >> 5;
    int jl = lane & 31;
    float carr[16];
#pragma unroll
    for (int m = 0; m < 16; ++m) carr[m] = 0.f;
    float cj = 0.f;
    float pA[16], pB[16];

    if (!bwd) {
        FWD_LOAD(pA, 0);
        FWD_LOAD(pB, 1);
        for (int it = 0; it < TT - 2; it += 2) {
            SCAN_CORE(pA, alphas_pre, it,
                      if (it + 2 < TT - 1) FWD_LOAD(pA, it + 2));
            SCAN_CORE(pB, alphas_pre, it + 1,
                      if (it + 3 < TT - 1) FWD_LOAD(pB, it + 3));
        }
        SCAN_CORE(pA, alphas_pre, TT - 2, );
        float mx = cj;
#pragma unroll
        for (int off = 16; off; off >>= 1) mx = fmaxf(mx, __shfl_xor(mx, off));
        float s = fexp2(cj - mx);
#pragma unroll
        for (int off = 16; off; off >>= 1) s += __shfl_xor(s, off);
        float lg = flog2(s);
        if (lane == 0) {
            logZ[n] = (mx + lg) * LN2;       // natural
            logZ[32 + n] = mx + lg;          // base-2 (for elbo)
        }
        if (lane < 32) out[2 + n * 32 + jl] = (cj - mx - lg) * LN2;
    } else {
        BWD_LOAD(pA, TT - 2);
        BWD_LOAD(pB, TT - 3);
        for (int it = TT - 2; it >= 2; it -= 2) {
            SCAN_CORE(pA, betas_next, it,
                      if (it - 2 >= 0) BWD_LOAD(pA, it - 2));
            SCAN_CORE(pB, betas_next, it - 1,
                      if (it - 3 >= 0) BWD_LOAD(pB, it - 3));
        }
        SCAN_CORE(pA, betas_next, 0, );
    }
}

// ---------------------------------------------------------------------------
// K13: elbo — per-block double partial to a PRIVATE slot (NO atomics).
// ---------------------------------------------------------------------------
__global__ __launch_bounds__(256) void elbo_kernel(
    const float* __restrict__ phiN, const float* __restrict__ alphas_pre,
    const float* __restrict__ betas_next, const float* __restrict__ logZ,
    double* __restrict__ epart)
{
    int t = blockIdx.x / NB;
    int n = blockIdx.x - t * NB;
    int tid = threadIdx.x;
    __shared__ float ap[32], bn[32];
    if (tid < 32) ap[tid] = alphas_pre[((size_t)t * NB + n) * SPW + tid];
    else if (tid < 64) bn[tid - 32] = betas_next[((size_t)t * NB + n) * SPW + (tid - 32)];
    __syncthreads();
    float lz2 = logZ[32 + n];
    size_t base = (size_t)(t * NB + n) * 1024;
    double local = 0.0;
#pragma unroll
    for (int e = tid; e < 1024; e += 256) {
        int i = e >> 5, j = e & 31;
        float ph2 = phiN[base + e];
        float lm2 = ap[i] + ph2 + bn[j] - lz2;
        local += (double)(fexp2(lm2) * (ph2 * LN2));
    }
#pragma unroll
    for (int off = 32; off; off >>= 1) local += __shfl_down(local, off);
    __shared__ double wsum[4];
    if ((tid & 63) == 0) wsum[tid >> 6] = local;
    __syncthreads();
    if (tid == 0) epart[blockIdx.x] = wsum[0] + wsum[1] + wsum[2] + wsum[3];
}

// ---------------------------------------------------------------------------
// K14: final — sum NTOK partials + logZ sum (kernel boundary = coherence).
// ---------------------------------------------------------------------------
__global__ __launch_bounds__(256) void final_kernel(
    const double* __restrict__ epart, const float* __restrict__ logZ,
    float* __restrict__ out)
{
    int tid = threadIdx.x;
    double local = 0.0;
    for (int i = tid; i < NTOK; i += 256) local += epart[i];
#pragma unroll
    for (int off = 32; off; off >>= 1) local += __shfl_down(local, off);
    __shared__ double wsum[4];
    if ((tid & 63) == 0) wsum[tid >> 6] = local;
    __syncthreads();
    if (tid == 0) {
        out[0] = (float)(wsum[0] + wsum[1] + wsum[2] + wsum[3]);
        float s = 0.f;
        for (int k = 0; k < NB; ++k) s += logZ[k];
        out[1] = s;
    }
}

// ---------------------------------------------------------------------------
extern "C" void kernel_launch(void* const* d_in, const int* in_sizes, int n_in,
                              void* d_out, int out_size, void* d_ws, size_t ws_size,
                              hipStream_t stream) {
    (void)in_sizes; (void)n_in; (void)out_size; (void)ws_size;
    const float* start_emb = (const float*)d_in[0];
    const float* sw1  = (const float*)d_in[1];
    const float* sb1  = (const float*)d_in[2];
    const float* sw2  = (const float*)d_in[3];
    const float* sb2  = (const float*)d_in[4];
    const float* sow  = (const float*)d_in[5];
    const float* state_emb = (const float*)d_in[7];
    const float* tw1  = (const float*)d_in[8];
    const float* tb1  = (const float*)d_in[9];
    const float* tw2  = (const float*)d_in[10];
    const float* tb2  = (const float*)d_in[11];
    const float* nsp  = (const float*)d_in[12];
    const float* pre_emb = (const float*)d_in[13];
    const float* ew1  = (const float*)d_in[14];
    const float* eb1  = (const float*)d_in[15];
    const float* ew2  = (const float*)d_in[16];
    const float* eb2  = (const float*)d_in[17];
    const float* eow  = (const float*)d_in[18];
    const float* eob  = (const float*)d_in[19];
    const int*   text = (const int*)d_in[20];
    const int*   w2s  = (const int*)d_in[21];

    float* ws = (float*)d_ws;
    float* TL      = ws + OFF_TL;
    float* s_tmp   = ws + OFF_STMP;
    float* startl  = ws + OFF_START;
    float* lse1    = ws + OFF_LSE1;
    unsigned* rmax = (unsigned*)(ws + OFF_RMAX);
    float* rsum    = ws + OFF_RSUM;
    float* den     = ws + OFF_DEN;
    float* logZ    = ws + OFF_LOGZ;
    float2* part   = (float2*)(ws + OFF_PART);
    double* epart  = (double*)(ws + OFF_EPART);
    unsigned short* Xp  = (unsigned short*)(ws + OFF_XP);
    unsigned short* Hp  = (unsigned short*)(ws + OFF_HP);
    unsigned short* W1p = (unsigned short*)(ws + OFF_W1P);
    unsigned short* W2p = (unsigned short*)(ws + OFF_W2P);
    unsigned short* Ap  = (unsigned short*)(ws + OFF_AP);
    unsigned short* Bp  = (unsigned short*)(ws + OFF_BP);
    float* ewT     = ws + OFF_EWT;
    float* Lm      = ws + OFF_L;
    float* phiN    = ws + OFF_PHI;
    float* res_e   = ws + OFF_RES_E;
    float* alph    = ws + OFF_ALPH;
    float* beta    = ws + OFF_BETA;
    int* cnt       = (int*)(ws + OFF_CNT);
    int* offs      = (int*)(ws + OFF_OFFS);
    int* cur       = (int*)(ws + OFF_CUR);
    int* ent       = (int*)(ws + OFF_ENT);
    float* out     = (float*)d_out;

    // pack inputs/weights (+ fused accumulator init); MLPs on MFMA
    pack_all_kernel<<<4496, 256, 0, stream>>>(start_emb, state_emb, pre_emb, nsp,
                                              sw1, tw1, ew1, sw2, tw2, ew2,
                                              Xp, Bp, W1p, W2p,
                                              rmax, rsum, cnt, s_tmp);
    gemm_layer1<<<dim3(2, 96), 256, 0, stream>>>(Xp, W1p, sb1, tb1, eb1, Hp);
    gemm_layer2<<<dim3(2, 96), 256, 0, stream>>>(Hp, W2p, sb2, tb2, eb2,
                                                 start_emb, state_emb, pre_emb,
                                                 sow, s_tmp, Ap, res_e);

    // transition path: restructured K=512 [hi|lo] TL GEMM + lse partials
    gemm_bt_kernel<<<dim3(32, 32), 256, 0, stream>>>(Ap, Bp, TL, part);

    // emission path (Ap/Bp dead now; ewT overwrites them)
    transpose_kernel<<<dim3(V_ / 32, H_ / 32), 256, 0, stream>>>(eow, ewT);
    em_logits_kernel<<<V_, 256, 0, stream>>>(res_e, ewT, eob, w2s, Lm, rmax);
    row_sum_kernel<<<V_ / 8, 256, 0, stream>>>(w2s, Lm, rmax, rsum);
    denom_hist_lse_kernel<<<16 + NITEM / 256 + 1024 + 1, 256, 0, stream>>>(
        rmax, rsum, den, text, w2s, cnt, part, lse1, s_tmp, startl);
    prefix_kernel<<<1, 1024, 0, stream>>>(cnt, offs, cur);
    fill_kernel<<<NITEM / 256, 256, 0, stream>>>(text, w2s, cur, ent);

    // phi assembly (obs inline, base-2 scaled) + scans + outputs
    phi_gather_kernel<<<C_, 256, 0, stream>>>(TL, offs, ent, lse1, startl,
                                              Lm, den, text, w2s, phiN);
    scan_kernel<<<2 * NB, 64, 0, stream>>>(phiN, alph, beta, logZ, out);
    elbo_kernel<<<NTOK, 256, 0, stream>>>(phiN, alph, beta, logZ, epart);
    final_kernel<<<1, 256, 0, stream>>>(epart, logZ, out);
}